// Round 2
// baseline (6076.345 us; speedup 1.0000x reference)
//
#include <hip/hip_runtime.h>

#define NATOMS 24
#define HIDD   61
#define NITERS 6

typedef unsigned short u16;
typedef unsigned int   u32;

__device__ __forceinline__ float bf2f(u16 v){
  union { u32 u; float f; } x; x.u = ((u32)v) << 16; return x.f;
}
__device__ __forceinline__ u16 f2bf(float f){
  union { float f; u32 u; } x; x.f = f;
  u32 u = x.u;
  return (u16)((u + 0x7fffu + ((u >> 16) & 1u)) >> 16);
}
__device__ __forceinline__ float sigm(float x){ return 1.f/(1.f + __expf(-x)); }
__device__ __forceinline__ float tanhx(float x){ return 1.f - 2.f/(__expf(2.f*x)+1.f); }

// ---------------------------------------------------------------------------
// h0[n,k] = k<61 ? relu(embed[x[n],k]) : ext[n, k-61]
__global__ void k_init_h(const int* __restrict__ x, const float* __restrict__ embed,
                         const float* __restrict__ ext, float* __restrict__ h, int N){
  int t = blockIdx.x*blockDim.x + threadIdx.x;
  if (t >= N*64) return;
  int n = t >> 6, k = t & 63;
  float v;
  if (k < HIDD) v = fmaxf(embed[x[n]*HIDD + k], 0.f);
  else          v = ext[n*3 + (k - HIDD)];
  h[t] = v;
}

// WihT[k,j] = Wih[j,k]  (192x64 -> 64x192), same for Whh
__global__ void k_transpose_w(const float* __restrict__ Wih, const float* __restrict__ Whh,
                              float* __restrict__ WihT, float* __restrict__ WhhT){
  int t = blockIdx.x*blockDim.x + threadIdx.x;
  if (t >= 192*64) return;
  int j = t / 64, k = t % 64;
  WihT[k*192 + j] = Wih[j*64 + k];
  WhhT[k*192 + j] = Whh[j*64 + k];
}

// ---------------------------------------------------------------------------
// W_edge chunk GEMM:  W[e - e0, :] = relu(ea[e]@We1 + be1) @ We2 + be2  (bf16 out)
// Block: 64 edges x 128 cols, K=128 fully in LDS; edge-MLP fused into A-load.
__global__ __launch_bounds__(256) void k_edge_gemm(
    const float* __restrict__ ea, const float* __restrict__ We1,
    const float* __restrict__ be1, const float* __restrict__ We2,
    const float* __restrict__ be2, u16* __restrict__ W, int e0, int e1)
{
  __shared__ float AsT[128][68];   // [k][row]
  __shared__ float Bs[32][128];
  int t = threadIdx.x;
  int erow0 = e0 + blockIdx.x * 64;
  int n0 = blockIdx.y * 128;

  // Phase A: AsT[c][row] = relu(ea[row]@We1 + be1)[c]
  {
    int row = t & 63;
    int c0 = (t >> 6) * 32;
    int e = erow0 + row;
    float a0=0.f,a1=0.f,a2=0.f,a3=0.f;
    if (e < e1){
      float4 av = *(const float4*)&ea[(size_t)e*4];
      a0=av.x; a1=av.y; a2=av.z; a3=av.w;
    }
    for (int cc = 0; cc < 32; ++cc){
      int c = c0 + cc;
      float v = be1[c] + a0*We1[c] + a1*We1[128+c] + a2*We1[256+c] + a3*We1[384+c];
      AsT[c][row] = fmaxf(v, 0.f);
    }
  }

  int tr4 = t >> 4;           // 0..15 -> rows tr4*4..+4
  int tc  = t & 15;           // 0..15 -> cols tc*8..+8
  int r0 = tr4*4, c0 = tc*8;
  float acc[4][8];
  #pragma unroll
  for (int i=0;i<4;++i)
    #pragma unroll
    for (int j=0;j<8;++j) acc[i][j]=0.f;

  for (int kb = 0; kb < 4; ++kb){
    __syncthreads();
    {
      int kr = t >> 3;            // 0..31
      int cc = (t & 7) * 16;
      const float* src = &We2[(size_t)(kb*32 + kr)*4096 + n0 + cc];
      float4 v0 = *(const float4*)(src);
      float4 v1 = *(const float4*)(src+4);
      float4 v2 = *(const float4*)(src+8);
      float4 v3 = *(const float4*)(src+12);
      *(float4*)&Bs[kr][cc]    = v0;
      *(float4*)&Bs[kr][cc+4]  = v1;
      *(float4*)&Bs[kr][cc+8]  = v2;
      *(float4*)&Bs[kr][cc+12] = v3;
    }
    __syncthreads();
    #pragma unroll 4
    for (int k = 0; k < 32; ++k){
      int kk = kb*32 + k;
      float4 a  = *(const float4*)&AsT[kk][r0];
      float4 b0 = *(const float4*)&Bs[k][c0];
      float4 b1 = *(const float4*)&Bs[k][c0+4];
      float av[4] = {a.x,a.y,a.z,a.w};
      float bv[8] = {b0.x,b0.y,b0.z,b0.w,b1.x,b1.y,b1.z,b1.w};
      #pragma unroll
      for (int i=0;i<4;++i)
        #pragma unroll
        for (int j=0;j<8;++j) acc[i][j] += av[i]*bv[j];
    }
  }

  float bias[8];
  #pragma unroll
  for (int j=0;j<8;++j) bias[j] = be2[n0 + c0 + j];
  #pragma unroll
  for (int i=0;i<4;++i){
    int e = erow0 + r0 + i;
    if (e < e1){
      u32 w0 = (u32)f2bf(acc[i][0]+bias[0]) | ((u32)f2bf(acc[i][1]+bias[1])<<16);
      u32 w1 = (u32)f2bf(acc[i][2]+bias[2]) | ((u32)f2bf(acc[i][3]+bias[3])<<16);
      u32 w2 = (u32)f2bf(acc[i][4]+bias[4]) | ((u32)f2bf(acc[i][5]+bias[5])<<16);
      u32 w3 = (u32)f2bf(acc[i][6]+bias[6]) | ((u32)f2bf(acc[i][7]+bias[7])<<16);
      uint4 o; o.x=w0; o.y=w1; o.z=w2; o.w=w3;
      *(uint4*)&W[(size_t)(e - e0)*4096 + n0 + c0] = o;
    }
  }
}

// ---------------------------------------------------------------------------
// msg + segment_sum: one wave per edge. lane k: acc = sum_h x[h]*W[e,h,k];
// atomic add into agg[dst, k].
__global__ __launch_bounds__(256) void k_msg(
    const int* __restrict__ ei, const float* __restrict__ h,
    const u16* __restrict__ W, float* __restrict__ agg,
    int e0, int e1, int E)
{
  int lane = threadIdx.x & 63;
  int e = e0 + blockIdx.x*4 + (threadIdx.x >> 6);
  if (e >= e1) return;
  int src = ei[e], dst = ei[E + e];
  float x = h[(size_t)src*64 + lane];
  const u16* Wp = W + (size_t)(e - e0)*4096;
  float acc = 0.f;
  #pragma unroll 8
  for (int hh = 0; hh < 64; ++hh){
    float xb = __shfl(x, hh, 64);
    acc += xb * bf2f(Wp[hh*64 + lane]);
  }
  unsafeAtomicAdd(&agg[(size_t)dst*64 + lane], acc);
}

// ---------------------------------------------------------------------------
// combine: m = relu(agg + h@root + conv_b); GRU -> hnext. 64 nodes per block.
__global__ __launch_bounds__(256) void k_combine(
    const float* __restrict__ hcur, const float* __restrict__ agg,
    const float* __restrict__ root, const float* __restrict__ convb,
    const float* __restrict__ WihT, const float* __restrict__ WhhT,
    const float* __restrict__ bih, const float* __restrict__ bhh,
    float* __restrict__ hnext, int N)
{
  __shared__ float hsT[64][76];   // [k][node]
  __shared__ float msT[64][76];
  __shared__ float ws[64][68];    // weight tile [k][j]
  int t = threadIdx.x;
  int n0 = blockIdx.x * 64;

  for (int idx = t; idx < 4096; idx += 256){
    int ni = idx >> 6, k = idx & 63;
    int n = n0 + ni;
    hsT[k][ni] = (n < N) ? hcur[(size_t)n*64 + k] : 0.f;
  }
  for (int idx = t; idx < 4096; idx += 256)
    ws[idx >> 6][idx & 63] = root[idx];
  __syncthreads();

  int tq = t >> 4, tr = t & 15;
  int ni0 = tq*4, j0 = tr*4;

  // m phase
  {
    float acc[4][4];
    #pragma unroll
    for (int i=0;i<4;++i)
      #pragma unroll
      for (int j=0;j<4;++j) acc[i][j] = 0.f;
    for (int k = 0; k < 64; ++k){
      float4 a  = *(const float4*)&hsT[k][ni0];
      float4 wv = *(const float4*)&ws[k][j0];
      float av[4]={a.x,a.y,a.z,a.w}, bv[4]={wv.x,wv.y,wv.z,wv.w};
      #pragma unroll
      for (int i=0;i<4;++i)
        #pragma unroll
        for (int j=0;j<4;++j) acc[i][j] += av[i]*bv[j];
    }
    #pragma unroll
    for (int i=0;i<4;++i){
      int n = n0 + ni0 + i;
      float agv[4] = {0.f,0.f,0.f,0.f};
      if (n < N){
        float4 ag = *(const float4*)&agg[(size_t)n*64 + j0];
        agv[0]=ag.x; agv[1]=ag.y; agv[2]=ag.z; agv[3]=ag.w;
      }
      #pragma unroll
      for (int j=0;j<4;++j)
        acc[i][j] = fmaxf(acc[i][j] + agv[j] + convb[j0+j], 0.f);
    }
    #pragma unroll
    for (int j=0;j<4;++j){
      float4 mv; mv.x=acc[0][j]; mv.y=acc[1][j]; mv.z=acc[2][j]; mv.w=acc[3][j];
      *(float4*)&msT[j0+j][ni0] = mv;
    }
  }

  float g[6][4][4];
  #pragma unroll
  for (int ct = 0; ct < 6; ++ct){
    __syncthreads();
    const float* WT = (ct < 3) ? WihT : WhhT;
    const float* bs = (ct < 3) ? bih  : bhh;
    int joff = (ct % 3) * 64;
    for (int idx = t; idx < 4096; idx += 256){
      int k = idx >> 6, j = idx & 63;
      ws[k][j] = WT[k*192 + joff + j];
    }
    __syncthreads();
    float acc[4][4];
    #pragma unroll
    for (int i=0;i<4;++i)
      #pragma unroll
      for (int j=0;j<4;++j) acc[i][j] = bs[joff + j0 + j];
    for (int k = 0; k < 64; ++k){
      float4 a  = (ct < 3) ? *(const float4*)&msT[k][ni0]
                           : *(const float4*)&hsT[k][ni0];
      float4 wv = *(const float4*)&ws[k][j0];
      float av[4]={a.x,a.y,a.z,a.w}, bv[4]={wv.x,wv.y,wv.z,wv.w};
      #pragma unroll
      for (int i=0;i<4;++i)
        #pragma unroll
        for (int j=0;j<4;++j) acc[i][j] += av[i]*bv[j];
    }
    #pragma unroll
    for (int i=0;i<4;++i)
      #pragma unroll
      for (int j=0;j<4;++j) g[ct][i][j] = acc[i][j];
  }

  // gates
  #pragma unroll
  for (int i=0;i<4;++i){
    int n = n0 + ni0 + i;
    if (n < N){
      float hv[4];
      #pragma unroll
      for (int j=0;j<4;++j){
        float rr = sigm(g[0][i][j] + g[3][i][j]);
        float zz = sigm(g[1][i][j] + g[4][i][j]);
        float hold = hsT[j0+j][ni0+i];
        float nn = tanhx(g[2][i][j] + rr*g[5][i][j]);
        hv[j] = (1.f - zz)*nn + zz*hold;
      }
      float4 o; o.x=hv[0]; o.y=hv[1]; o.z=hv[2]; o.w=hv[3];
      *(float4*)&hnext[(size_t)n*64 + j0] = o;
    }
  }
}

// ---------------------------------------------------------------------------
// final: out-MLP -> feat -> normalize -> fg_embed; classifier -> pred.
// One wave per node.
__global__ __launch_bounds__(256) void k_final(
    const float* __restrict__ h, const int* __restrict__ x, const float* __restrict__ ext,
    const float* __restrict__ Wo1, const float* __restrict__ bo1,
    const float* __restrict__ Wo2, const float* __restrict__ bo2,
    const float* __restrict__ Wc1, const float* __restrict__ bc1,
    const float* __restrict__ Wc2, const float* __restrict__ bc2,
    float* __restrict__ fg_out, float* __restrict__ pred_out, int N)
{
  int lane = threadIdx.x & 63;
  int n = blockIdx.x*4 + (threadIdx.x >> 6);
  if (n >= N) return;
  float hv = h[(size_t)n*64 + lane];

  float acc = bo1[lane];
  for (int k = 0; k < 64; ++k) acc += __shfl(hv, k, 64) * Wo1[k*64 + lane];
  float t1 = fmaxf(acc, 0.f);
  float acc2 = bo2[lane];
  for (int k = 0; k < 64; ++k) acc2 += __shfl(t1, k, 64) * Wo2[k*64 + lane];
  float o = acc2;

  int idxn = x[n];
  float exv = 0.f;
  if (lane < NATOMS)          exv = (lane == idxn) ? 1.f : 0.f;
  else if (lane < NATOMS + 3) exv = ext[n*3 + (lane - NATOMS)];

  float ss = o*o + exv*exv;
  #pragma unroll
  for (int off = 32; off > 0; off >>= 1) ss += __shfl_xor(ss, off, 64);
  float rn = 1.f / fmaxf(sqrtf(ss), 1e-12f);
  float fg1 = o * rn, fg2 = exv * rn;

  fg_out[(size_t)n*91 + lane] = fg1;
  if (lane < 27) fg_out[(size_t)n*91 + 64 + lane] = fg2;

  float tq0 = bc1[lane], tq1 = bc1[64+lane], tq2 = bc1[128+lane], tq3 = bc1[192+lane];
  for (int f = 0; f < 64; ++f){
    float fv = __shfl(fg1, f, 64);
    const float* wp = &Wc1[(size_t)f*256 + lane];
    tq0 += fv*wp[0]; tq1 += fv*wp[64]; tq2 += fv*wp[128]; tq3 += fv*wp[192];
  }
  for (int f = 0; f < 27; ++f){
    float fv = __shfl(fg2, f, 64);
    const float* wp = &Wc1[(size_t)(64+f)*256 + lane];
    tq0 += fv*wp[0]; tq1 += fv*wp[64]; tq2 += fv*wp[128]; tq3 += fv*wp[192];
  }
  tq0 = fmaxf(tq0, 0.f); tq1 = fmaxf(tq1, 0.f);
  tq2 = fmaxf(tq2, 0.f); tq3 = fmaxf(tq3, 0.f);

  float pc[18];
  #pragma unroll
  for (int c = 0; c < 18; ++c){
    pc[c] = tq0*Wc2[lane*18 + c] + tq1*Wc2[(64+lane)*18 + c]
          + tq2*Wc2[(128+lane)*18 + c] + tq3*Wc2[(192+lane)*18 + c];
  }
  float wv = 0.f;
  #pragma unroll
  for (int c = 0; c < 18; ++c){
    float v = pc[c];
    #pragma unroll
    for (int off = 32; off > 0; off >>= 1) v += __shfl_xor(v, off, 64);
    if (lane == c) wv = v + bc2[c];
  }
  if (lane < 18) pred_out[(size_t)n*18 + lane] = wv;
}

// ---------------------------------------------------------------------------
extern "C" void kernel_launch(void* const* d_in, const int* in_sizes, int n_in,
                              void* d_out, int out_size, void* d_ws, size_t ws_size,
                              hipStream_t stream)
{
  const int*   x    = (const int*)d_in[0];
  const int*   ei   = (const int*)d_in[1];
  const float* ea   = (const float*)d_in[2];
  const float* ext  = (const float*)d_in[3];
  const float* embed= (const float*)d_in[4];
  const float* We1  = (const float*)d_in[5];
  const float* be1  = (const float*)d_in[6];
  const float* We2  = (const float*)d_in[7];
  const float* be2  = (const float*)d_in[8];
  const float* root = (const float*)d_in[9];
  const float* convb= (const float*)d_in[10];
  const float* Wih  = (const float*)d_in[11];
  const float* Whh  = (const float*)d_in[12];
  const float* bih  = (const float*)d_in[13];
  const float* bhh  = (const float*)d_in[14];
  const float* Wo1  = (const float*)d_in[15];
  const float* bo1  = (const float*)d_in[16];
  const float* Wo2  = (const float*)d_in[17];
  const float* bo2  = (const float*)d_in[18];
  const float* Wc1  = (const float*)d_in[19];
  const float* bc1  = (const float*)d_in[20];
  const float* Wc2  = (const float*)d_in[21];
  const float* bc2  = (const float*)d_in[22];
  int N = in_sizes[0];
  int E = in_sizes[1] / 2;
  float* out = (float*)d_out;
  float* fg_out = out;
  float* pred_out = out + (size_t)N*91;

  char* w = (char*)d_ws;
  size_t remain = ws_size;
  auto alloc = [&](size_t bytes)->char*{
    size_t rb = (bytes + 255) & ~(size_t)255;
    if (rb > remain) return (char*)0;
    char* p = w; w += rb; remain -= rb; return p;
  };
  float* h_a  = (float*)alloc((size_t)N*64*4);
  float* h_b  = (float*)alloc((size_t)N*64*4);
  float* agg  = (float*)alloc((size_t)N*64*4);
  float* WihT = (float*)alloc(64*192*4);
  float* WhhT = (float*)alloc(64*192*4);
  if (!h_a || !h_b || !agg || !WihT || !WhhT) return;  // workspace too small to run at all

  u16* Wbf = (u16*)w;
  size_t avail = remain;
  size_t full_need = (size_t)E * 4096 * 2;
  bool full = (avail >= full_need);
  int CE = E;
  if (!full){
    CE = (int)(avail / ((size_t)4096*2));
    CE &= ~63;                 // multiple of 64 edges
    if (CE > E) CE = E;
  }

  k_init_h<<<dim3((N*64 + 255)/256), dim3(256), 0, stream>>>(x, embed, ext, h_a, N);
  k_transpose_w<<<dim3(48), dim3(256), 0, stream>>>(Wih, Whh, WihT, WhhT);

  if (full){
    k_edge_gemm<<<dim3((E + 63)/64, 32), dim3(256), 0, stream>>>(
        ea, We1, be1, We2, be2, Wbf, 0, E);
  }

  float* hc = h_a; float* hn = h_b;
  for (int it = 0; it < NITERS; ++it){
    hipMemsetAsync(agg, 0, (size_t)N*64*4, stream);
    if (full){
      k_msg<<<dim3((E + 3)/4), dim3(256), 0, stream>>>(ei, hc, Wbf, agg, 0, E, E);
    } else if (CE >= 64){
      for (int c0 = 0; c0 < E; c0 += CE){
        int c1 = c0 + CE; if (c1 > E) c1 = E;
        k_edge_gemm<<<dim3((c1 - c0 + 63)/64, 32), dim3(256), 0, stream>>>(
            ea, We1, be1, We2, be2, Wbf, c0, c1);
        k_msg<<<dim3((c1 - c0 + 3)/4), dim3(256), 0, stream>>>(ei, hc, Wbf, agg, c0, c1, E);
      }
    }
    k_combine<<<dim3((N + 63)/64), dim3(256), 0, stream>>>(
        hc, agg, root, convb, WihT, WhhT, bih, bhh, hn, N);
    float* tmp = hc; hc = hn; hn = tmp;
  }

  k_final<<<dim3((N + 3)/4), dim3(256), 0, stream>>>(
      hc, x, ext, Wo1, bo1, Wo2, bo2, Wc1, bc1, Wc2, bc2, fg_out, pred_out, N);
}

// Round 3
// 1321.097 us; speedup vs baseline: 4.5995x; 4.5995x over previous
//
#include <hip/hip_runtime.h>
#include <hip/hip_fp16.h>

#define NATOMS 24
#define HIDD   61
#define NITERS 6
#define CC     4          // c-columns per chunk
#define NCH    33         // chunks: 132 c-slots = 128 real + 1 bias + 3 zero
#define CTOT   132

typedef unsigned short u16;
typedef unsigned int   u32;
typedef _Float16 f16x8 __attribute__((ext_vector_type(8)));
typedef float    f32x4 __attribute__((ext_vector_type(4)));

__device__ __forceinline__ float sigm(float x){ return 1.f/(1.f + __expf(-x)); }
__device__ __forceinline__ float tanhx(float x){ return 1.f - 2.f/(__expf(2.f*x)+1.f); }
__device__ __forceinline__ u16 f2h(float f){ return __half_as_ushort(__float2half(f)); }

__device__ __forceinline__ f16x8 vmul8(f16x8 v, _Float16 s){
  f16x8 r;
  #pragma unroll
  for (int i=0;i<8;++i) r[i] = v[i]*s;
  return r;
}

// ---------------------------------------------------------------------------
__global__ void k_init_h(const int* __restrict__ x, const float* __restrict__ embed,
                         const float* __restrict__ ext, float* __restrict__ h, int N){
  int t = blockIdx.x*blockDim.x + threadIdx.x;
  if (t >= N*64) return;
  int n = t >> 6, k = t & 63;
  float v;
  if (k < HIDD) v = fmaxf(embed[x[n]*HIDD + k], 0.f);
  else          v = ext[n*3 + (k - HIDD)];
  h[t] = v;
}

__global__ void k_transpose_w(const float* __restrict__ Wih, const float* __restrict__ Whh,
                              float* __restrict__ WihT, float* __restrict__ WhhT){
  int t = blockIdx.x*blockDim.x + threadIdx.x;
  if (t >= 192*64) return;
  int j = t / 64, k = t % 64;
  WihT[k*192 + j] = Wih[j*64 + k];
  WhhT[k*192 + j] = Whh[j*64 + k];
}

// ---------------------------------------------------------------------------
// B_glob: fp16 frag-layout of We2R (+bias row c=128, zeros c=129..131).
// out[((ch*32 + f)*64 + l)*8 + j], f = cc*8 + kh*4 + ct:
//   c = ch*4+cc; h = kh*32 + (l>>4)*8 + j; n = ct*16 + (l&15)
//   val = c<128 ? We2[c][h*64+n] : (c==128 ? be2[h*64+n] : 0)
__global__ void k_prep_B(const float* __restrict__ We2, const float* __restrict__ be2,
                         u16* __restrict__ Bg){
  int tid = blockIdx.x*blockDim.x + threadIdx.x;
  if (tid >= NCH*32*64) return;
  int l  = tid & 63;
  int f  = (tid >> 6) & 31;
  int ch = tid >> 11;
  int cc = f >> 3, kh = (f >> 2) & 1, ct = f & 3;
  int c  = ch*CC + cc;
  int n  = ct*16 + (l & 15);
  int hb = kh*32 + (l >> 4)*8;
  u16 ov[8];
  #pragma unroll
  for (int j=0;j<8;++j){
    int hh = hb + j;
    float v = 0.f;
    if (c < 128)       v = We2[(size_t)c*4096 + hh*64 + n];
    else if (c == 128) v = be2[hh*64 + n];
    ov[j] = f2h(v);
  }
  uint4 o;
  o.x = (u32)ov[0] | ((u32)ov[1]<<16);
  o.y = (u32)ov[2] | ((u32)ov[3]<<16);
  o.z = (u32)ov[4] | ((u32)ov[5]<<16);
  o.w = (u32)ov[6] | ((u32)ov[7]<<16);
  *(uint4*)&Bg[(size_t)tid*8] = o;
}

// ---------------------------------------------------------------------------
// A_glob[c][Epad] fp16, c-major: A[c][e] = relu(ea[e]@We1 + be1)[c] (c<128),
// row 128 = 1.0, rows 129..131 = 0.
__global__ __launch_bounds__(256) void k_edge_mlp(
    const float* __restrict__ ea, const float* __restrict__ We1,
    const float* __restrict__ be1, u16* __restrict__ Ag, int E, int Epad)
{
  __shared__ float Al[128][66];
  int t = threadIdx.x;
  int e0 = blockIdx.x * 64;
  int el = t & 63, cg = t >> 6;
  int e = e0 + el;
  float4 av = make_float4(0,0,0,0);
  if (e < E) av = *(const float4*)&ea[(size_t)e*4];
  for (int cc = 0; cc < 32; ++cc){
    int c = cg*32 + cc;
    float v = be1[c] + av.x*We1[c] + av.y*We1[128+c] + av.z*We1[256+c] + av.w*We1[384+c];
    Al[c][el] = fmaxf(v, 0.f);
  }
  __syncthreads();
  for (int idx = t; idx < CTOT*4; idx += 256){
    int r = idx >> 2, q = idx & 3;     // 16 cols each
    u16 ov[16];
    #pragma unroll
    for (int i=0;i<16;++i){
      float v;
      if (r < 128)       v = Al[r][q*16 + i];
      else if (r == 128) v = 1.f;
      else               v = 0.f;
      ov[i] = f2h(v);
    }
    u16* dst = &Ag[(size_t)r*Epad + e0 + q*16];
    uint4 o0, o1;
    o0.x=(u32)ov[0]|((u32)ov[1]<<16);  o0.y=(u32)ov[2]|((u32)ov[3]<<16);
    o0.z=(u32)ov[4]|((u32)ov[5]<<16);  o0.w=(u32)ov[6]|((u32)ov[7]<<16);
    o1.x=(u32)ov[8]|((u32)ov[9]<<16);  o1.y=(u32)ov[10]|((u32)ov[11]<<16);
    o1.z=(u32)ov[12]|((u32)ov[13]<<16); o1.w=(u32)ov[14]|((u32)ov[15]<<16);
    *(uint4*)dst = o0;
    *(uint4*)(dst+8) = o1;
  }
}

// ---------------------------------------------------------------------------
// Fused msg + segment_sum via MFMA:
//   msg[e,k] = sum_{c,h} A[e,c]*v[e,h]*We2R[(c,h),k];  atomic-add into agg[dst].
// Block: 256 thr (4 waves), 256 edges. Wave: 64 edges x 64 k.
// v-frags in regs (loaded once); G = v * A[e,c] built per c; B double-buffered.
__global__ __launch_bounds__(256,1) void k_msg_mfma(
    const int* __restrict__ ei, const float* __restrict__ h,
    const u16* __restrict__ Ag, const u16* __restrict__ Bg,
    float* __restrict__ agg, int E, int Epad)
{
  __shared__ __align__(16) char smem[70656];
  u16* Blds = (u16*)smem;                 // 2 bufs x 16384 u16 (32KB each)
  u16* Alds = (u16*)(smem + 65536);       // 2 bufs x 1024 u16 (2KB each)
  int* dstl = (int*)(smem + 69632);       // [256]
  u16* vlds = (u16*)smem;                 // overlay on Blds buf0+1 (dead after prologue)

  int t = threadIdx.x;
  int lane = t & 63;
  int wv = t >> 6;
  int e0 = blockIdx.x * 256;

  // ---- stage v (gather h[src] -> fp16) + dst indices
  for (int q = t; q < 256*16; q += 256){
    int el = q >> 4, hq = q & 15;
    int e = e0 + el;
    float4 hv = make_float4(0,0,0,0);
    if (e < E){
      int s = ei[e];
      hv = *(const float4*)&h[(size_t)s*64 + hq*4];
    }
    if (hq == 0) dstl[el] = (e < E) ? ei[E + e] : -1;
    ushort4 pk;
    pk.x = f2h(hv.x); pk.y = f2h(hv.y); pk.z = f2h(hv.z); pk.w = f2h(hv.w);
    *(ushort4*)&vlds[el*64 + hq*4] = pk;
  }
  __syncthreads();

  // ---- load v-frags: wave wv owns edges [wv*64, wv*64+64)
  f16x8 vf[4][2];
  #pragma unroll
  for (int rt=0; rt<4; ++rt)
    #pragma unroll
    for (int kh=0; kh<2; ++kh)
      vf[rt][kh] = *(const f16x8*)&vlds[(wv*64 + rt*16 + (lane&15))*64 + kh*32 + (lane>>4)*8];
  __syncthreads();   // all waves done reading v; buf0 may be overwritten

  f32x4 acc[4][4];
  #pragma unroll
  for (int i=0;i<4;++i)
    #pragma unroll
    for (int j=0;j<4;++j)
      acc[i][j] = (f32x4){0.f,0.f,0.f,0.f};

  uint4 rb[8]; ushort4 ra;
  const int aRow = t >> 6, aCol = (t & 63)*4;

  // prologue: chunk 0 -> buf 0
  #pragma unroll
  for (int i=0;i<8;++i) rb[i] = *(const uint4*)&Bg[(size_t)0*16384 + t*64 + i*8];
  ra = *(const ushort4*)&Ag[(size_t)(0*CC + aRow)*Epad + e0 + aCol];
  #pragma unroll
  for (int i=0;i<8;++i) *(uint4*)&Blds[0*16384 + t*64 + i*8] = rb[i];
  *(ushort4*)&Alds[0*1024 + aRow*256 + aCol] = ra;
  __syncthreads();

  int cur = 0;
  for (int ch = 0; ch < NCH; ++ch){
    if (ch + 1 < NCH){
      #pragma unroll
      for (int i=0;i<8;++i) rb[i] = *(const uint4*)&Bg[(size_t)(ch+1)*16384 + t*64 + i*8];
      ra = *(const ushort4*)&Ag[(size_t)((ch+1)*CC + aRow)*Epad + e0 + aCol];
    }
    // ---- compute chunk from buf[cur]
    const u16* Bb = &Blds[cur*16384];
    const _Float16* Ab = (const _Float16*)&Alds[cur*1024];
    #pragma unroll
    for (int cl=0; cl<CC; ++cl){
      f16x8 bf0[4], bf1[4];
      #pragma unroll
      for (int ct=0; ct<4; ++ct){
        bf0[ct] = *(const f16x8*)&Bb[(cl*8 + ct)*512 + lane*8];
        bf1[ct] = *(const f16x8*)&Bb[(cl*8 + 4 + ct)*512 + lane*8];
      }
      #pragma unroll
      for (int rt=0; rt<4; ++rt){
        _Float16 ar = Ab[cl*256 + wv*64 + rt*16 + (lane&15)];
        f16x8 g0 = vmul8(vf[rt][0], ar);
        f16x8 g1 = vmul8(vf[rt][1], ar);
        #pragma unroll
        for (int ct=0; ct<4; ++ct){
          acc[rt][ct] = __builtin_amdgcn_mfma_f32_16x16x32_f16(g0, bf0[ct], acc[rt][ct], 0,0,0);
          acc[rt][ct] = __builtin_amdgcn_mfma_f32_16x16x32_f16(g1, bf1[ct], acc[rt][ct], 0,0,0);
        }
      }
    }
    if (ch + 1 < NCH){
      #pragma unroll
      for (int i=0;i<8;++i) *(uint4*)&Blds[(cur^1)*16384 + t*64 + i*8] = rb[i];
      *(ushort4*)&Alds[(cur^1)*1024 + aRow*256 + aCol] = ra;
    }
    __syncthreads();
    cur ^= 1;
  }

  // ---- epilogue: scatter-add. D layout: col=lane&15, row=(lane>>4)*4+reg
  #pragma unroll
  for (int rt=0; rt<4; ++rt){
    #pragma unroll
    for (int r=0; r<4; ++r){
      int el = wv*64 + rt*16 + (lane>>4)*4 + r;
      int dv = dstl[el];
      if (dv >= 0){
        #pragma unroll
        for (int ct=0; ct<4; ++ct){
          int kc = ct*16 + (lane&15);
          unsafeAtomicAdd(&agg[(size_t)dv*64 + kc], acc[rt][ct][r]);
        }
      }
    }
  }
}

// ---------------------------------------------------------------------------
__global__ __launch_bounds__(256) void k_combine(
    const float* __restrict__ hcur, const float* __restrict__ agg,
    const float* __restrict__ root, const float* __restrict__ convb,
    const float* __restrict__ WihT, const float* __restrict__ WhhT,
    const float* __restrict__ bih, const float* __restrict__ bhh,
    float* __restrict__ hnext, int N)
{
  __shared__ float hsT[64][76];
  __shared__ float msT[64][76];
  __shared__ float ws[64][68];
  int t = threadIdx.x;
  int n0 = blockIdx.x * 64;

  for (int idx = t; idx < 4096; idx += 256){
    int ni = idx >> 6, k = idx & 63;
    int n = n0 + ni;
    hsT[k][ni] = (n < N) ? hcur[(size_t)n*64 + k] : 0.f;
  }
  for (int idx = t; idx < 4096; idx += 256)
    ws[idx >> 6][idx & 63] = root[idx];
  __syncthreads();

  int tq = t >> 4, tr = t & 15;
  int ni0 = tq*4, j0 = tr*4;

  {
    float acc[4][4];
    #pragma unroll
    for (int i=0;i<4;++i)
      #pragma unroll
      for (int j=0;j<4;++j) acc[i][j] = 0.f;
    for (int k = 0; k < 64; ++k){
      float4 a  = *(const float4*)&hsT[k][ni0];
      float4 wv = *(const float4*)&ws[k][j0];
      float av[4]={a.x,a.y,a.z,a.w}, bv[4]={wv.x,wv.y,wv.z,wv.w};
      #pragma unroll
      for (int i=0;i<4;++i)
        #pragma unroll
        for (int j=0;j<4;++j) acc[i][j] += av[i]*bv[j];
    }
    #pragma unroll
    for (int i=0;i<4;++i){
      int n = n0 + ni0 + i;
      float agv[4] = {0.f,0.f,0.f,0.f};
      if (n < N){
        float4 ag = *(const float4*)&agg[(size_t)n*64 + j0];
        agv[0]=ag.x; agv[1]=ag.y; agv[2]=ag.z; agv[3]=ag.w;
      }
      #pragma unroll
      for (int j=0;j<4;++j)
        acc[i][j] = fmaxf(acc[i][j] + agv[j] + convb[j0+j], 0.f);
    }
    #pragma unroll
    for (int j=0;j<4;++j){
      float4 mv; mv.x=acc[0][j]; mv.y=acc[1][j]; mv.z=acc[2][j]; mv.w=acc[3][j];
      *(float4*)&msT[j0+j][ni0] = mv;
    }
  }

  float g[6][4][4];
  #pragma unroll
  for (int ct = 0; ct < 6; ++ct){
    __syncthreads();
    const float* WT = (ct < 3) ? WihT : WhhT;
    const float* bs = (ct < 3) ? bih  : bhh;
    int joff = (ct % 3) * 64;
    for (int idx = t; idx < 4096; idx += 256){
      int k = idx >> 6, j = idx & 63;
      ws[k][j] = WT[k*192 + joff + j];
    }
    __syncthreads();
    float acc[4][4];
    #pragma unroll
    for (int i=0;i<4;++i)
      #pragma unroll
      for (int j=0;j<4;++j) acc[i][j] = bs[joff + j0 + j];
    for (int k = 0; k < 64; ++k){
      float4 a  = (ct < 3) ? *(const float4*)&msT[k][ni0]
                           : *(const float4*)&hsT[k][ni0];
      float4 wv = *(const float4*)&ws[k][j0];
      float av[4]={a.x,a.y,a.z,a.w}, bv[4]={wv.x,wv.y,wv.z,wv.w};
      #pragma unroll
      for (int i=0;i<4;++i)
        #pragma unroll
        for (int j=0;j<4;++j) acc[i][j] += av[i]*bv[j];
    }
    #pragma unroll
    for (int i=0;i<4;++i)
      #pragma unroll
      for (int j=0;j<4;++j) g[ct][i][j] = acc[i][j];
  }

  #pragma unroll
  for (int i=0;i<4;++i){
    int n = n0 + ni0 + i;
    if (n < N){
      float hv[4];
      #pragma unroll
      for (int j=0;j<4;++j){
        float rr = sigm(g[0][i][j] + g[3][i][j]);
        float zz = sigm(g[1][i][j] + g[4][i][j]);
        float hold = hsT[j0+j][ni0+i];
        float nn = tanhx(g[2][i][j] + rr*g[5][i][j]);
        hv[j] = (1.f - zz)*nn + zz*hold;
      }
      float4 o; o.x=hv[0]; o.y=hv[1]; o.z=hv[2]; o.w=hv[3];
      *(float4*)&hnext[(size_t)n*64 + j0] = o;
    }
  }
}

// ---------------------------------------------------------------------------
__global__ __launch_bounds__(256) void k_final(
    const float* __restrict__ h, const int* __restrict__ x, const float* __restrict__ ext,
    const float* __restrict__ Wo1, const float* __restrict__ bo1,
    const float* __restrict__ Wo2, const float* __restrict__ bo2,
    const float* __restrict__ Wc1, const float* __restrict__ bc1,
    const float* __restrict__ Wc2, const float* __restrict__ bc2,
    float* __restrict__ fg_out, float* __restrict__ pred_out, int N)
{
  int lane = threadIdx.x & 63;
  int n = blockIdx.x*4 + (threadIdx.x >> 6);
  if (n >= N) return;
  float hv = h[(size_t)n*64 + lane];

  float acc = bo1[lane];
  for (int k = 0; k < 64; ++k) acc += __shfl(hv, k, 64) * Wo1[k*64 + lane];
  float t1 = fmaxf(acc, 0.f);
  float acc2 = bo2[lane];
  for (int k = 0; k < 64; ++k) acc2 += __shfl(t1, k, 64) * Wo2[k*64 + lane];
  float o = acc2;

  int idxn = x[n];
  float exv = 0.f;
  if (lane < NATOMS)          exv = (lane == idxn) ? 1.f : 0.f;
  else if (lane < NATOMS + 3) exv = ext[n*3 + (lane - NATOMS)];

  float ss = o*o + exv*exv;
  #pragma unroll
  for (int off = 32; off > 0; off >>= 1) ss += __shfl_xor(ss, off, 64);
  float rn = 1.f / fmaxf(sqrtf(ss), 1e-12f);
  float fg1 = o * rn, fg2 = exv * rn;

  fg_out[(size_t)n*91 + lane] = fg1;
  if (lane < 27) fg_out[(size_t)n*91 + 64 + lane] = fg2;

  float tq0 = bc1[lane], tq1 = bc1[64+lane], tq2 = bc1[128+lane], tq3 = bc1[192+lane];
  for (int f = 0; f < 64; ++f){
    float fv = __shfl(fg1, f, 64);
    const float* wp = &Wc1[(size_t)f*256 + lane];
    tq0 += fv*wp[0]; tq1 += fv*wp[64]; tq2 += fv*wp[128]; tq3 += fv*wp[192];
  }
  for (int f = 0; f < 27; ++f){
    float fv = __shfl(fg2, f, 64);
    const float* wp = &Wc1[(size_t)(64+f)*256 + lane];
    tq0 += fv*wp[0]; tq1 += fv*wp[64]; tq2 += fv*wp[128]; tq3 += fv*wp[192];
  }
  tq0 = fmaxf(tq0, 0.f); tq1 = fmaxf(tq1, 0.f);
  tq2 = fmaxf(tq2, 0.f); tq3 = fmaxf(tq3, 0.f);

  float pc[18];
  #pragma unroll
  for (int c = 0; c < 18; ++c){
    pc[c] = tq0*Wc2[lane*18 + c] + tq1*Wc2[(64+lane)*18 + c]
          + tq2*Wc2[(128+lane)*18 + c] + tq3*Wc2[(192+lane)*18 + c];
  }
  float wv = 0.f;
  #pragma unroll
  for (int c = 0; c < 18; ++c){
    float v = pc[c];
    #pragma unroll
    for (int off = 32; off > 0; off >>= 1) v += __shfl_xor(v, off, 64);
    if (lane == c) wv = v + bc2[c];
  }
  if (lane < 18) pred_out[(size_t)n*18 + lane] = wv;
}

// ---------------------------------------------------------------------------
extern "C" void kernel_launch(void* const* d_in, const int* in_sizes, int n_in,
                              void* d_out, int out_size, void* d_ws, size_t ws_size,
                              hipStream_t stream)
{
  const int*   x    = (const int*)d_in[0];
  const int*   ei   = (const int*)d_in[1];
  const float* ea   = (const float*)d_in[2];
  const float* ext  = (const float*)d_in[3];
  const float* embed= (const float*)d_in[4];
  const float* We1  = (const float*)d_in[5];
  const float* be1  = (const float*)d_in[6];
  const float* We2  = (const float*)d_in[7];
  const float* be2  = (const float*)d_in[8];
  const float* root = (const float*)d_in[9];
  const float* convb= (const float*)d_in[10];
  const float* Wih  = (const float*)d_in[11];
  const float* Whh  = (const float*)d_in[12];
  const float* bih  = (const float*)d_in[13];
  const float* bhh  = (const float*)d_in[14];
  const float* Wo1  = (const float*)d_in[15];
  const float* bo1  = (const float*)d_in[16];
  const float* Wo2  = (const float*)d_in[17];
  const float* bo2  = (const float*)d_in[18];
  const float* Wc1  = (const float*)d_in[19];
  const float* bc1  = (const float*)d_in[20];
  const float* Wc2  = (const float*)d_in[21];
  const float* bc2  = (const float*)d_in[22];
  int N = in_sizes[0];
  int E = in_sizes[1] / 2;
  float* out = (float*)d_out;
  float* fg_out = out;
  float* pred_out = out + (size_t)N*91;

  int nblk = (E + 255) / 256;
  int Epad = nblk * 256;

  char* w = (char*)d_ws;
  size_t remain = ws_size;
  auto alloc = [&](size_t bytes)->char*{
    size_t rb = (bytes + 255) & ~(size_t)255;
    if (rb > remain) return (char*)0;
    char* p = w; w += rb; remain -= rb; return p;
  };
  float* h_a  = (float*)alloc((size_t)N*64*4);
  float* h_b  = (float*)alloc((size_t)N*64*4);
  float* agg  = (float*)alloc((size_t)N*64*4);
  float* WihT = (float*)alloc(64*192*4);
  float* WhhT = (float*)alloc(64*192*4);
  u16*   Ag   = (u16*)alloc((size_t)CTOT*Epad*2);
  u16*   Bg   = (u16*)alloc((size_t)NCH*32768);
  if (!h_a || !h_b || !agg || !WihT || !WhhT || !Ag || !Bg) return;

  k_init_h<<<dim3((N*64 + 255)/256), dim3(256), 0, stream>>>(x, embed, ext, h_a, N);
  k_transpose_w<<<dim3(48), dim3(256), 0, stream>>>(Wih, Whh, WihT, WhhT);
  k_prep_B<<<dim3((NCH*32*64 + 255)/256), dim3(256), 0, stream>>>(We2, be2, Bg);
  k_edge_mlp<<<dim3(Epad/64), dim3(256), 0, stream>>>(ea, We1, be1, Ag, E, Epad);

  float* hc = h_a; float* hn = h_b;
  for (int it = 0; it < NITERS; ++it){
    hipMemsetAsync(agg, 0, (size_t)N*64*4, stream);
    k_msg_mfma<<<dim3(nblk), dim3(256), 0, stream>>>(ei, hc, Ag, Bg, agg, E, Epad);
    k_combine<<<dim3((N + 63)/64), dim3(256), 0, stream>>>(
        hc, agg, root, convb, WihT, WhhT, bih, bhh, hn, N);
    float* tmp = hc; hc = hn; hn = tmp;
  }

  k_final<<<dim3((N + 3)/4), dim3(256), 0, stream>>>(
      hc, x, ext, Wo1, bo1, Wo2, bo2, Wc1, bc1, Wc2, bc2, fg_out, pred_out, N);
}

// Round 4
// 1208.518 us; speedup vs baseline: 5.0279x; 1.0932x over previous
//
#include <hip/hip_runtime.h>
#include <hip/hip_fp16.h>

#define NATOMS 24
#define HIDD   61
#define NITERS 6
#define CC     4          // c-columns per chunk
#define NCH    33         // chunks: 132 c-slots = 128 real + 1 bias + 3 zero
#define CTOT   132

typedef unsigned short u16;
typedef unsigned int   u32;
typedef _Float16 f16x8 __attribute__((ext_vector_type(8)));
typedef float    f32x4 __attribute__((ext_vector_type(4)));

__device__ __forceinline__ float sigm(float x){ return 1.f/(1.f + __expf(-x)); }
__device__ __forceinline__ float tanhx(float x){ return 1.f - 2.f/(__expf(2.f*x)+1.f); }
__device__ __forceinline__ u16 f2h(float f){ return __half_as_ushort(__float2half(f)); }

__device__ __forceinline__ f16x8 vmul8(f16x8 v, _Float16 s){
  f16x8 r;
  #pragma unroll
  for (int i=0;i<8;++i) r[i] = v[i]*s;
  return r;
}

// ---------------------------------------------------------------------------
__global__ void k_init_h(const int* __restrict__ x, const float* __restrict__ embed,
                         const float* __restrict__ ext, float* __restrict__ h, int N){
  int t = blockIdx.x*blockDim.x + threadIdx.x;
  if (t >= N*64) return;
  int n = t >> 6, k = t & 63;
  float v;
  if (k < HIDD) v = fmaxf(embed[x[n]*HIDD + k], 0.f);
  else          v = ext[n*3 + (k - HIDD)];
  h[t] = v;
}

__global__ void k_transpose_w(const float* __restrict__ Wih, const float* __restrict__ Whh,
                              float* __restrict__ WihT, float* __restrict__ WhhT){
  int t = blockIdx.x*blockDim.x + threadIdx.x;
  if (t >= 192*64) return;
  int j = t / 64, k = t % 64;
  WihT[k*192 + j] = Wih[j*64 + k];
  WhhT[k*192 + j] = Whh[j*64 + k];
}

// ---------------------------------------------------------------------------
// B_glob: fp16 frag-layout of We2R (+bias row c=128, zeros c=129..131).
__global__ void k_prep_B(const float* __restrict__ We2, const float* __restrict__ be2,
                         u16* __restrict__ Bg){
  int tid = blockIdx.x*blockDim.x + threadIdx.x;
  if (tid >= NCH*32*64) return;
  int l  = tid & 63;
  int f  = (tid >> 6) & 31;
  int ch = tid >> 11;
  int cc = f >> 3, kh = (f >> 2) & 1, ct = f & 3;
  int c  = ch*CC + cc;
  int n  = ct*16 + (l & 15);
  int hb = kh*32 + (l >> 4)*8;
  u16 ov[8];
  #pragma unroll
  for (int j=0;j<8;++j){
    int hh = hb + j;
    float v = 0.f;
    if (c < 128)       v = We2[(size_t)c*4096 + hh*64 + n];
    else if (c == 128) v = be2[hh*64 + n];
    ov[j] = f2h(v);
  }
  uint4 o;
  o.x = (u32)ov[0] | ((u32)ov[1]<<16);
  o.y = (u32)ov[2] | ((u32)ov[3]<<16);
  o.z = (u32)ov[4] | ((u32)ov[5]<<16);
  o.w = (u32)ov[6] | ((u32)ov[7]<<16);
  *(uint4*)&Bg[(size_t)tid*8] = o;
}

// ---------------------------------------------------------------------------
// A_glob[c][Epad] fp16, c-major: A[c][e] = relu(ea[e]@We1 + be1)[c] (c<128),
// row 128 = 1.0, rows 129..131 = 0.
__global__ __launch_bounds__(256) void k_edge_mlp(
    const float* __restrict__ ea, const float* __restrict__ We1,
    const float* __restrict__ be1, u16* __restrict__ Ag, int E, int Epad)
{
  __shared__ float Al[128][66];
  int t = threadIdx.x;
  int e0 = blockIdx.x * 64;
  int el = t & 63, cg = t >> 6;
  int e = e0 + el;
  float4 av = make_float4(0,0,0,0);
  if (e < E) av = *(const float4*)&ea[(size_t)e*4];
  for (int cc = 0; cc < 32; ++cc){
    int c = cg*32 + cc;
    float v = be1[c] + av.x*We1[c] + av.y*We1[128+c] + av.z*We1[256+c] + av.w*We1[384+c];
    Al[c][el] = fmaxf(v, 0.f);
  }
  __syncthreads();
  for (int idx = t; idx < CTOT*4; idx += 256){
    int r = idx >> 2, q = idx & 3;     // 16 cols each
    u16 ov[16];
    #pragma unroll
    for (int i=0;i<16;++i){
      float v;
      if (r < 128)       v = Al[r][q*16 + i];
      else if (r == 128) v = 1.f;
      else               v = 0.f;
      ov[i] = f2h(v);
    }
    u16* dst = &Ag[(size_t)r*Epad + e0 + q*16];
    uint4 o0, o1;
    o0.x=(u32)ov[0]|((u32)ov[1]<<16);  o0.y=(u32)ov[2]|((u32)ov[3]<<16);
    o0.z=(u32)ov[4]|((u32)ov[5]<<16);  o0.w=(u32)ov[6]|((u32)ov[7]<<16);
    o1.x=(u32)ov[8]|((u32)ov[9]<<16);  o1.y=(u32)ov[10]|((u32)ov[11]<<16);
    o1.z=(u32)ov[12]|((u32)ov[13]<<16); o1.w=(u32)ov[14]|((u32)ov[15]<<16);
    *(uint4*)dst = o0;
    *(uint4*)(dst+8) = o1;
  }
}

// ---------------------------------------------------------------------------
// Fused msg + segment_sum via MFMA, v4: no LDS staging (B/A from L2, v direct
// gather), chunk range split across blockIdx.y for occupancy.
__global__ __launch_bounds__(256,3) void k_msg_mfma(
    const int* __restrict__ ei, const float* __restrict__ h,
    const u16* __restrict__ Ag, const u16* __restrict__ Bg,
    float* __restrict__ agg, int E, int Epad)
{
  __shared__ int dstl[256];
  int t = threadIdx.x;
  int lane = t & 63;
  int wv = t >> 6;
  int e0 = blockIdx.x * 256;
  int y = blockIdx.y;
  int ch0 = (y == 0) ? 0 : (1 + y*8);     // [0,9) [9,17) [17,25) [25,33)
  int ch1 = 1 + (y+1)*8;

  // dst indices (cooperative, coalesced)
  {
    int e = e0 + t;
    dstl[t] = (e < E) ? ei[E + e] : -1;
  }

  // v-frags: direct gather from h + cvt to f16. Lane holds v[e][hb..hb+8),
  // e = wv*64 + rt*16 + (lane&15), hb = kh*32 + (lane>>4)*8.
  f16x8 vf[4][2];
  #pragma unroll
  for (int rt=0; rt<4; ++rt){
    int e = e0 + wv*64 + rt*16 + (lane&15);
    int src = (e < E) ? ei[e] : 0;
    const float* hp = &h[(size_t)src*64 + (lane>>4)*8];
    #pragma unroll
    for (int kh=0; kh<2; ++kh){
      float4 a = *(const float4*)&hp[kh*32];
      float4 b = *(const float4*)&hp[kh*32+4];
      f16x8 v;
      v[0]=(_Float16)a.x; v[1]=(_Float16)a.y; v[2]=(_Float16)a.z; v[3]=(_Float16)a.w;
      v[4]=(_Float16)b.x; v[5]=(_Float16)b.y; v[6]=(_Float16)b.z; v[7]=(_Float16)b.w;
      vf[rt][kh] = v;
    }
  }
  __syncthreads();

  f32x4 acc[4][4];
  #pragma unroll
  for (int i=0;i<4;++i)
    #pragma unroll
    for (int j=0;j<4;++j)
      acc[i][j] = (f32x4){0.f,0.f,0.f,0.f};

  const u16* Arow = Ag + e0 + wv*64 + (lane & 15);

  for (int ch = ch0; ch < ch1; ++ch){
    const u16* Bc = Bg + (size_t)ch*16384 + lane*8;
    const u16* Ac = Arow + (size_t)ch*CC*Epad;
    #pragma unroll
    for (int cl=0; cl<CC; ++cl){
      // A scalars for this c (per-rt, 16-lane broadcast; L1-hot)
      _Float16 ar[4];
      #pragma unroll
      for (int rt=0; rt<4; ++rt)
        ar[rt] = *(const _Float16*)&Ac[(size_t)cl*Epad + rt*16];
      // B frags direct from L2 (1 KB coalesced per frag)
      f16x8 bf[8];
      #pragma unroll
      for (int f=0; f<8; ++f)
        bf[f] = *(const f16x8*)&Bc[(size_t)(cl*8 + f)*512];
      #pragma unroll
      for (int rt=0; rt<4; ++rt){
        f16x8 g0 = vmul8(vf[rt][0], ar[rt]);
        f16x8 g1 = vmul8(vf[rt][1], ar[rt]);
        #pragma unroll
        for (int ct=0; ct<4; ++ct){
          acc[rt][ct] = __builtin_amdgcn_mfma_f32_16x16x32_f16(g0, bf[ct],   acc[rt][ct], 0,0,0);
          acc[rt][ct] = __builtin_amdgcn_mfma_f32_16x16x32_f16(g1, bf[4+ct], acc[rt][ct], 0,0,0);
        }
      }
    }
  }

  // epilogue: scatter-add. D layout: col=lane&15, row=(lane>>4)*4+reg
  #pragma unroll
  for (int rt=0; rt<4; ++rt){
    #pragma unroll
    for (int r=0; r<4; ++r){
      int el = wv*64 + rt*16 + (lane>>4)*4 + r;
      int dv = dstl[el];
      if (dv >= 0){
        #pragma unroll
        for (int ct=0; ct<4; ++ct){
          int kc = ct*16 + (lane&15);
          unsafeAtomicAdd(&agg[(size_t)dv*64 + kc], acc[rt][ct][r]);
        }
      }
    }
  }
}

// ---------------------------------------------------------------------------
__global__ __launch_bounds__(256) void k_combine(
    const float* __restrict__ hcur, const float* __restrict__ agg,
    const float* __restrict__ root, const float* __restrict__ convb,
    const float* __restrict__ WihT, const float* __restrict__ WhhT,
    const float* __restrict__ bih, const float* __restrict__ bhh,
    float* __restrict__ hnext, int N)
{
  __shared__ float hsT[64][76];
  __shared__ float msT[64][76];
  __shared__ float ws[64][68];
  int t = threadIdx.x;
  int n0 = blockIdx.x * 64;

  for (int idx = t; idx < 4096; idx += 256){
    int ni = idx >> 6, k = idx & 63;
    int n = n0 + ni;
    hsT[k][ni] = (n < N) ? hcur[(size_t)n*64 + k] : 0.f;
  }
  for (int idx = t; idx < 4096; idx += 256)
    ws[idx >> 6][idx & 63] = root[idx];
  __syncthreads();

  int tq = t >> 4, tr = t & 15;
  int ni0 = tq*4, j0 = tr*4;

  {
    float acc[4][4];
    #pragma unroll
    for (int i=0;i<4;++i)
      #pragma unroll
      for (int j=0;j<4;++j) acc[i][j] = 0.f;
    for (int k = 0; k < 64; ++k){
      float4 a  = *(const float4*)&hsT[k][ni0];
      float4 wv = *(const float4*)&ws[k][j0];
      float av[4]={a.x,a.y,a.z,a.w}, bv[4]={wv.x,wv.y,wv.z,wv.w};
      #pragma unroll
      for (int i=0;i<4;++i)
        #pragma unroll
        for (int j=0;j<4;++j) acc[i][j] += av[i]*bv[j];
    }
    #pragma unroll
    for (int i=0;i<4;++i){
      int n = n0 + ni0 + i;
      float agv[4] = {0.f,0.f,0.f,0.f};
      if (n < N){
        float4 ag = *(const float4*)&agg[(size_t)n*64 + j0];
        agv[0]=ag.x; agv[1]=ag.y; agv[2]=ag.z; agv[3]=ag.w;
      }
      #pragma unroll
      for (int j=0;j<4;++j)
        acc[i][j] = fmaxf(acc[i][j] + agv[j] + convb[j0+j], 0.f);
    }
    #pragma unroll
    for (int j=0;j<4;++j){
      float4 mv; mv.x=acc[0][j]; mv.y=acc[1][j]; mv.z=acc[2][j]; mv.w=acc[3][j];
      *(float4*)&msT[j0+j][ni0] = mv;
    }
  }

  float g[6][4][4];
  #pragma unroll
  for (int ct = 0; ct < 6; ++ct){
    __syncthreads();
    const float* WT = (ct < 3) ? WihT : WhhT;
    const float* bs = (ct < 3) ? bih  : bhh;
    int joff = (ct % 3) * 64;
    for (int idx = t; idx < 4096; idx += 256){
      int k = idx >> 6, j = idx & 63;
      ws[k][j] = WT[k*192 + joff + j];
    }
    __syncthreads();
    float acc[4][4];
    #pragma unroll
    for (int i=0;i<4;++i)
      #pragma unroll
      for (int j=0;j<4;++j) acc[i][j] = bs[joff + j0 + j];
    for (int k = 0; k < 64; ++k){
      float4 a  = (ct < 3) ? *(const float4*)&msT[k][ni0]
                           : *(const float4*)&hsT[k][ni0];
      float4 wv = *(const float4*)&ws[k][j0];
      float av[4]={a.x,a.y,a.z,a.w}, bv[4]={wv.x,wv.y,wv.z,wv.w};
      #pragma unroll
      for (int i=0;i<4;++i)
        #pragma unroll
        for (int j=0;j<4;++j) acc[i][j] += av[i]*bv[j];
    }
    #pragma unroll
    for (int i=0;i<4;++i)
      #pragma unroll
      for (int j=0;j<4;++j) g[ct][i][j] = acc[i][j];
  }

  #pragma unroll
  for (int i=0;i<4;++i){
    int n = n0 + ni0 + i;
    if (n < N){
      float hv[4];
      #pragma unroll
      for (int j=0;j<4;++j){
        float rr = sigm(g[0][i][j] + g[3][i][j]);
        float zz = sigm(g[1][i][j] + g[4][i][j]);
        float hold = hsT[j0+j][ni0+i];
        float nn = tanhx(g[2][i][j] + rr*g[5][i][j]);
        hv[j] = (1.f - zz)*nn + zz*hold;
      }
      float4 o; o.x=hv[0]; o.y=hv[1]; o.z=hv[2]; o.w=hv[3];
      *(float4*)&hnext[(size_t)n*64 + j0] = o;
    }
  }
}

// ---------------------------------------------------------------------------
__global__ __launch_bounds__(256) void k_final(
    const float* __restrict__ h, const int* __restrict__ x, const float* __restrict__ ext,
    const float* __restrict__ Wo1, const float* __restrict__ bo1,
    const float* __restrict__ Wo2, const float* __restrict__ bo2,
    const float* __restrict__ Wc1, const float* __restrict__ bc1,
    const float* __restrict__ Wc2, const float* __restrict__ bc2,
    float* __restrict__ fg_out, float* __restrict__ pred_out, int N)
{
  int lane = threadIdx.x & 63;
  int n = blockIdx.x*4 + (threadIdx.x >> 6);
  if (n >= N) return;
  float hv = h[(size_t)n*64 + lane];

  float acc = bo1[lane];
  for (int k = 0; k < 64; ++k) acc += __shfl(hv, k, 64) * Wo1[k*64 + lane];
  float t1 = fmaxf(acc, 0.f);
  float acc2 = bo2[lane];
  for (int k = 0; k < 64; ++k) acc2 += __shfl(t1, k, 64) * Wo2[k*64 + lane];
  float o = acc2;

  int idxn = x[n];
  float exv = 0.f;
  if (lane < NATOMS)          exv = (lane == idxn) ? 1.f : 0.f;
  else if (lane < NATOMS + 3) exv = ext[n*3 + (lane - NATOMS)];

  float ss = o*o + exv*exv;
  #pragma unroll
  for (int off = 32; off > 0; off >>= 1) ss += __shfl_xor(ss, off, 64);
  float rn = 1.f / fmaxf(sqrtf(ss), 1e-12f);
  float fg1 = o * rn, fg2 = exv * rn;

  fg_out[(size_t)n*91 + lane] = fg1;
  if (lane < 27) fg_out[(size_t)n*91 + 64 + lane] = fg2;

  float tq0 = bc1[lane], tq1 = bc1[64+lane], tq2 = bc1[128+lane], tq3 = bc1[192+lane];
  for (int f = 0; f < 64; ++f){
    float fv = __shfl(fg1, f, 64);
    const float* wp = &Wc1[(size_t)f*256 + lane];
    tq0 += fv*wp[0]; tq1 += fv*wp[64]; tq2 += fv*wp[128]; tq3 += fv*wp[192];
  }
  for (int f = 0; f < 27; ++f){
    float fv = __shfl(fg2, f, 64);
    const float* wp = &Wc1[(size_t)(64+f)*256 + lane];
    tq0 += fv*wp[0]; tq1 += fv*wp[64]; tq2 += fv*wp[128]; tq3 += fv*wp[192];
  }
  tq0 = fmaxf(tq0, 0.f); tq1 = fmaxf(tq1, 0.f);
  tq2 = fmaxf(tq2, 0.f); tq3 = fmaxf(tq3, 0.f);

  float pc[18];
  #pragma unroll
  for (int c = 0; c < 18; ++c){
    pc[c] = tq0*Wc2[lane*18 + c] + tq1*Wc2[(64+lane)*18 + c]
          + tq2*Wc2[(128+lane)*18 + c] + tq3*Wc2[(192+lane)*18 + c];
  }
  float wv = 0.f;
  #pragma unroll
  for (int c = 0; c < 18; ++c){
    float v = pc[c];
    #pragma unroll
    for (int off = 32; off > 0; off >>= 1) v += __shfl_xor(v, off, 64);
    if (lane == c) wv = v + bc2[c];
  }
  if (lane < 18) pred_out[(size_t)n*18 + lane] = wv;
}

// ---------------------------------------------------------------------------
extern "C" void kernel_launch(void* const* d_in, const int* in_sizes, int n_in,
                              void* d_out, int out_size, void* d_ws, size_t ws_size,
                              hipStream_t stream)
{
  const int*   x    = (const int*)d_in[0];
  const int*   ei   = (const int*)d_in[1];
  const float* ea   = (const float*)d_in[2];
  const float* ext  = (const float*)d_in[3];
  const float* embed= (const float*)d_in[4];
  const float* We1  = (const float*)d_in[5];
  const float* be1  = (const float*)d_in[6];
  const float* We2  = (const float*)d_in[7];
  const float* be2  = (const float*)d_in[8];
  const float* root = (const float*)d_in[9];
  const float* convb= (const float*)d_in[10];
  const float* Wih  = (const float*)d_in[11];
  const float* Whh  = (const float*)d_in[12];
  const float* bih  = (const float*)d_in[13];
  const float* bhh  = (const float*)d_in[14];
  const float* Wo1  = (const float*)d_in[15];
  const float* bo1  = (const float*)d_in[16];
  const float* Wo2  = (const float*)d_in[17];
  const float* bo2  = (const float*)d_in[18];
  const float* Wc1  = (const float*)d_in[19];
  const float* bc1  = (const float*)d_in[20];
  const float* Wc2  = (const float*)d_in[21];
  const float* bc2  = (const float*)d_in[22];
  int N = in_sizes[0];
  int E = in_sizes[1] / 2;
  float* out = (float*)d_out;
  float* fg_out = out;
  float* pred_out = out + (size_t)N*91;

  int nblk = (E + 255) / 256;
  int Epad = nblk * 256;

  char* w = (char*)d_ws;
  size_t remain = ws_size;
  auto alloc = [&](size_t bytes)->char*{
    size_t rb = (bytes + 255) & ~(size_t)255;
    if (rb > remain) return (char*)0;
    char* p = w; w += rb; remain -= rb; return p;
  };
  float* h_a  = (float*)alloc((size_t)N*64*4);
  float* h_b  = (float*)alloc((size_t)N*64*4);
  float* agg  = (float*)alloc((size_t)N*64*4);
  float* WihT = (float*)alloc(64*192*4);
  float* WhhT = (float*)alloc(64*192*4);
  u16*   Ag   = (u16*)alloc((size_t)CTOT*Epad*2);
  u16*   Bg   = (u16*)alloc((size_t)NCH*32768);
  if (!h_a || !h_b || !agg || !WihT || !WhhT || !Ag || !Bg) return;

  k_init_h<<<dim3((N*64 + 255)/256), dim3(256), 0, stream>>>(x, embed, ext, h_a, N);
  k_transpose_w<<<dim3(48), dim3(256), 0, stream>>>(Wih, Whh, WihT, WhhT);
  k_prep_B<<<dim3((NCH*32*64 + 255)/256), dim3(256), 0, stream>>>(We2, be2, Bg);
  k_edge_mlp<<<dim3(Epad/64), dim3(256), 0, stream>>>(ea, We1, be1, Ag, E, Epad);

  float* hc = h_a; float* hn = h_b;
  for (int it = 0; it < NITERS; ++it){
    hipMemsetAsync(agg, 0, (size_t)N*64*4, stream);
    k_msg_mfma<<<dim3(nblk, 4), dim3(256), 0, stream>>>(ei, hc, Ag, Bg, agg, E, Epad);
    k_combine<<<dim3((N + 63)/64), dim3(256), 0, stream>>>(
        hc, agg, root, convb, WihT, WhhT, bih, bhh, hn, N);
    float* tmp = hc; hc = hn; hn = tmp;
  }

  k_final<<<dim3((N + 3)/4), dim3(256), 0, stream>>>(
      hc, x, ext, Wo1, bo1, Wo2, bo2, Wc1, bc1, Wc2, bc2, fg_out, pred_out, N);
}

// Round 5
// 1201.634 us; speedup vs baseline: 5.0567x; 1.0057x over previous
//
#include <hip/hip_runtime.h>
#include <hip/hip_fp16.h>

#define NATOMS 24
#define HIDD   61
#define NITERS 6
#define CC     4          // c-columns per chunk
#define NCH    33         // chunks: 132 c-slots = 128 real + 1 bias + 3 zero
#define CTOT   132

typedef unsigned short u16;
typedef unsigned int   u32;
typedef _Float16 f16x8 __attribute__((ext_vector_type(8)));
typedef float    f32x4 __attribute__((ext_vector_type(4)));

#define GLOAD_LDS16(g, l) __builtin_amdgcn_global_load_lds( \
    (const __attribute__((address_space(1))) void*)(g), \
    (__attribute__((address_space(3))) void*)(l), 16, 0, 0)

__device__ __forceinline__ float sigm(float x){ return 1.f/(1.f + __expf(-x)); }
__device__ __forceinline__ float tanhx(float x){ return 1.f - 2.f/(__expf(2.f*x)+1.f); }
__device__ __forceinline__ u16 f2h(float f){ return __half_as_ushort(__float2half(f)); }

__device__ __forceinline__ f16x8 vmul8(f16x8 v, _Float16 s){
  f16x8 r;
  #pragma unroll
  for (int i=0;i<8;++i) r[i] = v[i]*s;
  return r;
}

// ---------------------------------------------------------------------------
__global__ void k_init_h(const int* __restrict__ x, const float* __restrict__ embed,
                         const float* __restrict__ ext, float* __restrict__ h, int N){
  int t = blockIdx.x*blockDim.x + threadIdx.x;
  if (t >= N*64) return;
  int n = t >> 6, k = t & 63;
  float v;
  if (k < HIDD) v = fmaxf(embed[x[n]*HIDD + k], 0.f);
  else          v = ext[n*3 + (k - HIDD)];
  h[t] = v;
}

__global__ void k_transpose_w(const float* __restrict__ Wih, const float* __restrict__ Whh,
                              float* __restrict__ WihT, float* __restrict__ WhhT){
  int t = blockIdx.x*blockDim.x + threadIdx.x;
  if (t >= 192*64) return;
  int j = t / 64, k = t % 64;
  WihT[k*192 + j] = Wih[j*64 + k];
  WhhT[k*192 + j] = Whh[j*64 + k];
}

// ---------------------------------------------------------------------------
// B_glob: fp16 frag-layout of We2R (+bias row c=128, zeros c=129..131).
__global__ void k_prep_B(const float* __restrict__ We2, const float* __restrict__ be2,
                         u16* __restrict__ Bg){
  int tid = blockIdx.x*blockDim.x + threadIdx.x;
  if (tid >= NCH*32*64) return;
  int l  = tid & 63;
  int f  = (tid >> 6) & 31;
  int ch = tid >> 11;
  int cc = f >> 3, kh = (f >> 2) & 1, ct = f & 3;
  int c  = ch*CC + cc;
  int n  = ct*16 + (l & 15);
  int hb = kh*32 + (l >> 4)*8;
  u16 ov[8];
  #pragma unroll
  for (int j=0;j<8;++j){
    int hh = hb + j;
    float v = 0.f;
    if (c < 128)       v = We2[(size_t)c*4096 + hh*64 + n];
    else if (c == 128) v = be2[hh*64 + n];
    ov[j] = f2h(v);
  }
  uint4 o;
  o.x = (u32)ov[0] | ((u32)ov[1]<<16);
  o.y = (u32)ov[2] | ((u32)ov[3]<<16);
  o.z = (u32)ov[4] | ((u32)ov[5]<<16);
  o.w = (u32)ov[6] | ((u32)ov[7]<<16);
  *(uint4*)&Bg[(size_t)tid*8] = o;
}

// ---------------------------------------------------------------------------
// A_glob[c][Epad] fp16, c-major: A[c][e] = relu(ea[e]@We1 + be1)[c] (c<128),
// row 128 = 1.0, rows 129..131 = 0.
__global__ __launch_bounds__(256) void k_edge_mlp(
    const float* __restrict__ ea, const float* __restrict__ We1,
    const float* __restrict__ be1, u16* __restrict__ Ag, int E, int Epad)
{
  __shared__ float Al[128][66];
  int t = threadIdx.x;
  int e0 = blockIdx.x * 64;
  int el = t & 63, cg = t >> 6;
  int e = e0 + el;
  float4 av = make_float4(0,0,0,0);
  if (e < E) av = *(const float4*)&ea[(size_t)e*4];
  for (int cc = 0; cc < 32; ++cc){
    int c = cg*32 + cc;
    float v = be1[c] + av.x*We1[c] + av.y*We1[128+c] + av.z*We1[256+c] + av.w*We1[384+c];
    Al[c][el] = fmaxf(v, 0.f);
  }
  __syncthreads();
  for (int idx = t; idx < CTOT*4; idx += 256){
    int r = idx >> 2, q = idx & 3;     // 16 cols each
    u16 ov[16];
    #pragma unroll
    for (int i=0;i<16;++i){
      float v;
      if (r < 128)       v = Al[r][q*16 + i];
      else if (r == 128) v = 1.f;
      else               v = 0.f;
      ov[i] = f2h(v);
    }
    u16* dst = &Ag[(size_t)r*Epad + e0 + q*16];
    uint4 o0, o1;
    o0.x=(u32)ov[0]|((u32)ov[1]<<16);  o0.y=(u32)ov[2]|((u32)ov[3]<<16);
    o0.z=(u32)ov[4]|((u32)ov[5]<<16);  o0.w=(u32)ov[6]|((u32)ov[7]<<16);
    o1.x=(u32)ov[8]|((u32)ov[9]<<16);  o1.y=(u32)ov[10]|((u32)ov[11]<<16);
    o1.z=(u32)ov[12]|((u32)ov[13]<<16); o1.w=(u32)ov[14]|((u32)ov[15]<<16);
    *(uint4*)dst = o0;
    *(uint4*)(dst+8) = o1;
  }
}

// ---------------------------------------------------------------------------
// Fused msg + segment_sum via MFMA, v5: B chunk staged to LDS once per block
// via global_load_lds (width 16), single-buffered; chunk range split across
// blockIdx.y; v-frags gathered直接 to registers.
__global__ __launch_bounds__(256,3) void k_msg_mfma(
    const int* __restrict__ ei, const float* __restrict__ h,
    const u16* __restrict__ Ag, const u16* __restrict__ Bg,
    float* __restrict__ agg, int E, int Epad)
{
  __shared__ __align__(16) u16 Blds[16384];   // 32 KB, one chunk
  __shared__ int dstl[256];
  int t = threadIdx.x;
  int lane = t & 63;
  int wv = t >> 6;
  int e0 = blockIdx.x * 256;
  int y = blockIdx.y;
  int ch0 = (y == 0) ? 0 : (1 + y*8);     // [0,9) [9,17) [17,25) [25,33)
  int ch1 = 1 + (y+1)*8;

  // dst indices (cooperative, coalesced)
  {
    int e = e0 + t;
    dstl[t] = (e < E) ? ei[E + e] : -1;
  }

  // v-frags: direct gather from h + cvt to f16. Lane holds v[e][hb..hb+8),
  // e = wv*64 + rt*16 + (lane&15), hb = kh*32 + (lane>>4)*8.
  f16x8 vf[4][2];
  #pragma unroll
  for (int rt=0; rt<4; ++rt){
    int e = e0 + wv*64 + rt*16 + (lane&15);
    int src = (e < E) ? ei[e] : 0;
    const float* hp = &h[(size_t)src*64 + (lane>>4)*8];
    #pragma unroll
    for (int kh=0; kh<2; ++kh){
      float4 a = *(const float4*)&hp[kh*32];
      float4 b = *(const float4*)&hp[kh*32+4];
      f16x8 v;
      v[0]=(_Float16)a.x; v[1]=(_Float16)a.y; v[2]=(_Float16)a.z; v[3]=(_Float16)a.w;
      v[4]=(_Float16)b.x; v[5]=(_Float16)b.y; v[6]=(_Float16)b.z; v[7]=(_Float16)b.w;
      vf[rt][kh] = v;
    }
  }

  f32x4 acc[4][4];
  #pragma unroll
  for (int i=0;i<4;++i)
    #pragma unroll
    for (int j=0;j<4;++j)
      acc[i][j] = (f32x4){0.f,0.f,0.f,0.f};

  const u16* Arow = Ag + e0 + wv*64 + (lane & 15);

  for (int ch = ch0; ch < ch1; ++ch){
    __syncthreads();   // prev compute done before Blds overwrite (no-op first iter)
    // stage chunk (32 KB): wave wv, round r -> bytes [r*4096 + wv*1024, +1024)
    const char* gsrc = (const char*)(Bg + (size_t)ch*16384);
    #pragma unroll
    for (int r=0;r<8;++r){
      int off = r*4096 + wv*1024 + lane*16;
      GLOAD_LDS16(gsrc + off, (char*)Blds + r*4096 + wv*1024);
    }
    // A scalars for the whole chunk (one burst; L1-hot)
    const u16* Ac = Arow + (size_t)ch*CC*Epad;
    _Float16 ar[4][4];
    #pragma unroll
    for (int cl=0;cl<4;++cl)
      #pragma unroll
      for (int rt=0;rt<4;++rt)
        ar[cl][rt] = *(const _Float16*)&Ac[(size_t)cl*Epad + rt*16];
    __syncthreads();   // staging complete (vmcnt drained by barrier)

    #pragma unroll
    for (int cl=0; cl<CC; ++cl){
      f16x8 bf[8];
      #pragma unroll
      for (int f=0; f<8; ++f)
        bf[f] = *(const f16x8*)&Blds[(cl*8 + f)*512 + lane*8];
      #pragma unroll
      for (int rt=0; rt<4; ++rt){
        f16x8 g0 = vmul8(vf[rt][0], ar[cl][rt]);
        f16x8 g1 = vmul8(vf[rt][1], ar[cl][rt]);
        #pragma unroll
        for (int ct=0; ct<4; ++ct){
          acc[rt][ct] = __builtin_amdgcn_mfma_f32_16x16x32_f16(g0, bf[ct],   acc[rt][ct], 0,0,0);
          acc[rt][ct] = __builtin_amdgcn_mfma_f32_16x16x32_f16(g1, bf[4+ct], acc[rt][ct], 0,0,0);
        }
      }
    }
  }

  // epilogue: scatter-add. D layout: col=lane&15, row=(lane>>4)*4+reg
  #pragma unroll
  for (int rt=0; rt<4; ++rt){
    #pragma unroll
    for (int r=0; r<4; ++r){
      int el = wv*64 + rt*16 + (lane>>4)*4 + r;
      int dv = dstl[el];
      if (dv >= 0){
        #pragma unroll
        for (int ct=0; ct<4; ++ct){
          int kc = ct*16 + (lane&15);
          unsafeAtomicAdd(&agg[(size_t)dv*64 + kc], acc[rt][ct][r]);
        }
      }
    }
  }
}

// ---------------------------------------------------------------------------
__global__ __launch_bounds__(256) void k_combine(
    const float* __restrict__ hcur, const float* __restrict__ agg,
    const float* __restrict__ root, const float* __restrict__ convb,
    const float* __restrict__ WihT, const float* __restrict__ WhhT,
    const float* __restrict__ bih, const float* __restrict__ bhh,
    float* __restrict__ hnext, int N)
{
  __shared__ float hsT[64][76];
  __shared__ float msT[64][76];
  __shared__ float ws[64][68];
  int t = threadIdx.x;
  int n0 = blockIdx.x * 64;

  for (int idx = t; idx < 4096; idx += 256){
    int ni = idx >> 6, k = idx & 63;
    int n = n0 + ni;
    hsT[k][ni] = (n < N) ? hcur[(size_t)n*64 + k] : 0.f;
  }
  for (int idx = t; idx < 4096; idx += 256)
    ws[idx >> 6][idx & 63] = root[idx];
  __syncthreads();

  int tq = t >> 4, tr = t & 15;
  int ni0 = tq*4, j0 = tr*4;

  {
    float acc[4][4];
    #pragma unroll
    for (int i=0;i<4;++i)
      #pragma unroll
      for (int j=0;j<4;++j) acc[i][j] = 0.f;
    for (int k = 0; k < 64; ++k){
      float4 a  = *(const float4*)&hsT[k][ni0];
      float4 wv = *(const float4*)&ws[k][j0];
      float av[4]={a.x,a.y,a.z,a.w}, bv[4]={wv.x,wv.y,wv.z,wv.w};
      #pragma unroll
      for (int i=0;i<4;++i)
        #pragma unroll
        for (int j=0;j<4;++j) acc[i][j] += av[i]*bv[j];
    }
    #pragma unroll
    for (int i=0;i<4;++i){
      int n = n0 + ni0 + i;
      float agv[4] = {0.f,0.f,0.f,0.f};
      if (n < N){
        float4 ag = *(const float4*)&agg[(size_t)n*64 + j0];
        agv[0]=ag.x; agv[1]=ag.y; agv[2]=ag.z; agv[3]=ag.w;
      }
      #pragma unroll
      for (int j=0;j<4;++j)
        acc[i][j] = fmaxf(acc[i][j] + agv[j] + convb[j0+j], 0.f);
    }
    #pragma unroll
    for (int j=0;j<4;++j){
      float4 mv; mv.x=acc[0][j]; mv.y=acc[1][j]; mv.z=acc[2][j]; mv.w=acc[3][j];
      *(float4*)&msT[j0+j][ni0] = mv;
    }
  }

  float g[6][4][4];
  #pragma unroll
  for (int ct = 0; ct < 6; ++ct){
    __syncthreads();
    const float* WT = (ct < 3) ? WihT : WhhT;
    const float* bs = (ct < 3) ? bih  : bhh;
    int joff = (ct % 3) * 64;
    for (int idx = t; idx < 4096; idx += 256){
      int k = idx >> 6, j = idx & 63;
      ws[k][j] = WT[k*192 + joff + j];
    }
    __syncthreads();
    float acc[4][4];
    #pragma unroll
    for (int i=0;i<4;++i)
      #pragma unroll
      for (int j=0;j<4;++j) acc[i][j] = bs[joff + j0 + j];
    for (int k = 0; k < 64; ++k){
      float4 a  = (ct < 3) ? *(const float4*)&msT[k][ni0]
                           : *(const float4*)&hsT[k][ni0];
      float4 wv = *(const float4*)&ws[k][j0];
      float av[4]={a.x,a.y,a.z,a.w}, bv[4]={wv.x,wv.y,wv.z,wv.w};
      #pragma unroll
      for (int i=0;i<4;++i)
        #pragma unroll
        for (int j=0;j<4;++j) acc[i][j] += av[i]*bv[j];
    }
    #pragma unroll
    for (int i=0;i<4;++i)
      #pragma unroll
      for (int j=0;j<4;++j) g[ct][i][j] = acc[i][j];
  }

  #pragma unroll
  for (int i=0;i<4;++i){
    int n = n0 + ni0 + i;
    if (n < N){
      float hv[4];
      #pragma unroll
      for (int j=0;j<4;++j){
        float rr = sigm(g[0][i][j] + g[3][i][j]);
        float zz = sigm(g[1][i][j] + g[4][i][j]);
        float hold = hsT[j0+j][ni0+i];
        float nn = tanhx(g[2][i][j] + rr*g[5][i][j]);
        hv[j] = (1.f - zz)*nn + zz*hold;
      }
      float4 o; o.x=hv[0]; o.y=hv[1]; o.z=hv[2]; o.w=hv[3];
      *(float4*)&hnext[(size_t)n*64 + j0] = o;
    }
  }
}

// ---------------------------------------------------------------------------
__global__ __launch_bounds__(256) void k_final(
    const float* __restrict__ h, const int* __restrict__ x, const float* __restrict__ ext,
    const float* __restrict__ Wo1, const float* __restrict__ bo1,
    const float* __restrict__ Wo2, const float* __restrict__ bo2,
    const float* __restrict__ Wc1, const float* __restrict__ bc1,
    const float* __restrict__ Wc2, const float* __restrict__ bc2,
    float* __restrict__ fg_out, float* __restrict__ pred_out, int N)
{
  int lane = threadIdx.x & 63;
  int n = blockIdx.x*4 + (threadIdx.x >> 6);
  if (n >= N) return;
  float hv = h[(size_t)n*64 + lane];

  float acc = bo1[lane];
  for (int k = 0; k < 64; ++k) acc += __shfl(hv, k, 64) * Wo1[k*64 + lane];
  float t1 = fmaxf(acc, 0.f);
  float acc2 = bo2[lane];
  for (int k = 0; k < 64; ++k) acc2 += __shfl(t1, k, 64) * Wo2[k*64 + lane];
  float o = acc2;

  int idxn = x[n];
  float exv = 0.f;
  if (lane < NATOMS)          exv = (lane == idxn) ? 1.f : 0.f;
  else if (lane < NATOMS + 3) exv = ext[n*3 + (lane - NATOMS)];

  float ss = o*o + exv*exv;
  #pragma unroll
  for (int off = 32; off > 0; off >>= 1) ss += __shfl_xor(ss, off, 64);
  float rn = 1.f / fmaxf(sqrtf(ss), 1e-12f);
  float fg1 = o * rn, fg2 = exv * rn;

  fg_out[(size_t)n*91 + lane] = fg1;
  if (lane < 27) fg_out[(size_t)n*91 + 64 + lane] = fg2;

  float tq0 = bc1[lane], tq1 = bc1[64+lane], tq2 = bc1[128+lane], tq3 = bc1[192+lane];
  for (int f = 0; f < 64; ++f){
    float fv = __shfl(fg1, f, 64);
    const float* wp = &Wc1[(size_t)f*256 + lane];
    tq0 += fv*wp[0]; tq1 += fv*wp[64]; tq2 += fv*wp[128]; tq3 += fv*wp[192];
  }
  for (int f = 0; f < 27; ++f){
    float fv = __shfl(fg2, f, 64);
    const float* wp = &Wc1[(size_t)(64+f)*256 + lane];
    tq0 += fv*wp[0]; tq1 += fv*wp[64]; tq2 += fv*wp[128]; tq3 += fv*wp[192];
  }
  tq0 = fmaxf(tq0, 0.f); tq1 = fmaxf(tq1, 0.f);
  tq2 = fmaxf(tq2, 0.f); tq3 = fmaxf(tq3, 0.f);

  float pc[18];
  #pragma unroll
  for (int c = 0; c < 18; ++c){
    pc[c] = tq0*Wc2[lane*18 + c] + tq1*Wc2[(64+lane)*18 + c]
          + tq2*Wc2[(128+lane)*18 + c] + tq3*Wc2[(192+lane)*18 + c];
  }
  float wv = 0.f;
  #pragma unroll
  for (int c = 0; c < 18; ++c){
    float v = pc[c];
    #pragma unroll
    for (int off = 32; off > 0; off >>= 1) v += __shfl_xor(v, off, 64);
    if (lane == c) wv = v + bc2[c];
  }
  if (lane < 18) pred_out[(size_t)n*18 + lane] = wv;
}

// ---------------------------------------------------------------------------
extern "C" void kernel_launch(void* const* d_in, const int* in_sizes, int n_in,
                              void* d_out, int out_size, void* d_ws, size_t ws_size,
                              hipStream_t stream)
{
  const int*   x    = (const int*)d_in[0];
  const int*   ei   = (const int*)d_in[1];
  const float* ea   = (const float*)d_in[2];
  const float* ext  = (const float*)d_in[3];
  const float* embed= (const float*)d_in[4];
  const float* We1  = (const float*)d_in[5];
  const float* be1  = (const float*)d_in[6];
  const float* We2  = (const float*)d_in[7];
  const float* be2  = (const float*)d_in[8];
  const float* root = (const float*)d_in[9];
  const float* convb= (const float*)d_in[10];
  const float* Wih  = (const float*)d_in[11];
  const float* Whh  = (const float*)d_in[12];
  const float* bih  = (const float*)d_in[13];
  const float* bhh  = (const float*)d_in[14];
  const float* Wo1  = (const float*)d_in[15];
  const float* bo1  = (const float*)d_in[16];
  const float* Wo2  = (const float*)d_in[17];
  const float* bo2  = (const float*)d_in[18];
  const float* Wc1  = (const float*)d_in[19];
  const float* bc1  = (const float*)d_in[20];
  const float* Wc2  = (const float*)d_in[21];
  const float* bc2  = (const float*)d_in[22];
  int N = in_sizes[0];
  int E = in_sizes[1] / 2;
  float* out = (float*)d_out;
  float* fg_out = out;
  float* pred_out = out + (size_t)N*91;

  int nblk = (E + 255) / 256;
  int Epad = nblk * 256;

  char* w = (char*)d_ws;
  size_t remain = ws_size;
  auto alloc = [&](size_t bytes)->char*{
    size_t rb = (bytes + 255) & ~(size_t)255;
    if (rb > remain) return (char*)0;
    char* p = w; w += rb; remain -= rb; return p;
  };
  float* h_a  = (float*)alloc((size_t)N*64*4);
  float* h_b  = (float*)alloc((size_t)N*64*4);
  float* agg  = (float*)alloc((size_t)N*64*4);
  float* WihT = (float*)alloc(64*192*4);
  float* WhhT = (float*)alloc(64*192*4);
  u16*   Ag   = (u16*)alloc((size_t)CTOT*Epad*2);
  u16*   Bg   = (u16*)alloc((size_t)NCH*32768);
  if (!h_a || !h_b || !agg || !WihT || !WhhT || !Ag || !Bg) return;

  k_init_h<<<dim3((N*64 + 255)/256), dim3(256), 0, stream>>>(x, embed, ext, h_a, N);
  k_transpose_w<<<dim3(48), dim3(256), 0, stream>>>(Wih, Whh, WihT, WhhT);
  k_prep_B<<<dim3((NCH*32*64 + 255)/256), dim3(256), 0, stream>>>(We2, be2, Bg);
  k_edge_mlp<<<dim3(Epad/64), dim3(256), 0, stream>>>(ea, We1, be1, Ag, E, Epad);

  float* hc = h_a; float* hn = h_b;
  for (int it = 0; it < NITERS; ++it){
    hipMemsetAsync(agg, 0, (size_t)N*64*4, stream);
    k_msg_mfma<<<dim3(nblk, 4), dim3(256), 0, stream>>>(ei, hc, Ag, Bg, agg, E, Epad);
    k_combine<<<dim3((N + 63)/64), dim3(256), 0, stream>>>(
        hc, agg, root, convb, WihT, WhhT, bih, bhh, hn, N);
    float* tmp = hc; hc = hn; hn = tmp;
  }

  k_final<<<dim3((N + 3)/4), dim3(256), 0, stream>>>(
      hc, x, ext, Wo1, bo1, Wo2, bo2, Wc1, bc1, Wc2, bc2, fg_out, pred_out, N);
}

// Round 6
// 835.595 us; speedup vs baseline: 7.2719x; 1.4381x over previous
//
#include <hip/hip_runtime.h>
#include <hip/hip_fp16.h>

#define NATOMS 24
#define HIDD   61
#define NITERS 6
#define CC     4          // c-columns per chunk
#define NCH    33         // chunks: 132 c-slots = 128 real + 1 bias + 3 zero
#define CTOT   132

typedef unsigned short u16;
typedef unsigned int   u32;
typedef _Float16 f16x8 __attribute__((ext_vector_type(8)));
typedef float    f32x4 __attribute__((ext_vector_type(4)));

#define GLOAD_LDS16(g, l) __builtin_amdgcn_global_load_lds( \
    (const __attribute__((address_space(1))) void*)(g), \
    (__attribute__((address_space(3))) void*)(l), 16, 0, 0)

__device__ __forceinline__ float sigm(float x){ return 1.f/(1.f + __expf(-x)); }
__device__ __forceinline__ float tanhx(float x){ return 1.f - 2.f/(__expf(2.f*x)+1.f); }
__device__ __forceinline__ u16 f2h(float f){ return __half_as_ushort(__float2half(f)); }

__device__ __forceinline__ f16x8 vmul8(f16x8 v, _Float16 s){
  f16x8 r;
  #pragma unroll
  for (int i=0;i<8;++i) r[i] = v[i]*s;
  return r;
}

// ---------------------------------------------------------------------------
__global__ void k_init_h(const int* __restrict__ x, const float* __restrict__ embed,
                         const float* __restrict__ ext, float* __restrict__ h, int N){
  int t = blockIdx.x*blockDim.x + threadIdx.x;
  if (t >= N*64) return;
  int n = t >> 6, k = t & 63;
  float v;
  if (k < HIDD) v = fmaxf(embed[x[n]*HIDD + k], 0.f);
  else          v = ext[n*3 + (k - HIDD)];
  h[t] = v;
}

__global__ void k_transpose_w(const float* __restrict__ Wih, const float* __restrict__ Whh,
                              float* __restrict__ WihT, float* __restrict__ WhhT){
  int t = blockIdx.x*blockDim.x + threadIdx.x;
  if (t >= 192*64) return;
  int j = t / 64, k = t % 64;
  WihT[k*192 + j] = Wih[j*64 + k];
  WhhT[k*192 + j] = Whh[j*64 + k];
}

// ---------------------------------------------------------------------------
// B_glob: fp16 frag-layout of We2R (+bias row c=128, zeros c=129..131),
// k-split-friendly order: frag fi = ((ct*NCH + ch)*CC + cc)*2 + kh.
// Per frag (1 KB): lane l, elem j -> We2R[c][(kh*32 + (l>>4)*8 + j)*64 + ct*16 + (l&15)]
__global__ void k_prep_B(const float* __restrict__ We2, const float* __restrict__ be2,
                         u16* __restrict__ Bg){
  int tid = blockIdx.x*blockDim.x + threadIdx.x;
  if (tid >= NCH*32*64) return;
  int l  = tid & 63;
  int fi = tid >> 6;            // 0..1055
  int kh = fi & 1;
  int cc = (fi >> 1) & 3;
  int t2 = fi >> 3;             // ct*NCH + ch
  int ch = t2 % NCH;
  int ct = t2 / NCH;
  int c  = ch*CC + cc;
  int n  = ct*16 + (l & 15);
  int hb = kh*32 + (l >> 4)*8;
  u16 ov[8];
  #pragma unroll
  for (int j=0;j<8;++j){
    int hh = hb + j;
    float v = 0.f;
    if (c < 128)       v = We2[(size_t)c*4096 + hh*64 + n];
    else if (c == 128) v = be2[hh*64 + n];
    ov[j] = f2h(v);
  }
  uint4 o;
  o.x = (u32)ov[0] | ((u32)ov[1]<<16);
  o.y = (u32)ov[2] | ((u32)ov[3]<<16);
  o.z = (u32)ov[4] | ((u32)ov[5]<<16);
  o.w = (u32)ov[6] | ((u32)ov[7]<<16);
  *(uint4*)&Bg[(size_t)fi*512 + l*8] = o;
}

// ---------------------------------------------------------------------------
// A_glob[c][Epad] fp16, c-major: A[c][e] = relu(ea[e]@We1 + be1)[c] (c<128),
// row 128 = 1.0, rows 129..131 = 0.
__global__ __launch_bounds__(256) void k_edge_mlp(
    const float* __restrict__ ea, const float* __restrict__ We1,
    const float* __restrict__ be1, u16* __restrict__ Ag, int E, int Epad)
{
  __shared__ float Al[128][66];
  int t = threadIdx.x;
  int e0 = blockIdx.x * 64;
  int el = t & 63, cg = t >> 6;
  int e = e0 + el;
  float4 av = make_float4(0,0,0,0);
  if (e < E) av = *(const float4*)&ea[(size_t)e*4];
  for (int cc = 0; cc < 32; ++cc){
    int c = cg*32 + cc;
    float v = be1[c] + av.x*We1[c] + av.y*We1[128+c] + av.z*We1[256+c] + av.w*We1[384+c];
    Al[c][el] = fmaxf(v, 0.f);
  }
  __syncthreads();
  for (int idx = t; idx < CTOT*4; idx += 256){
    int r = idx >> 2, q = idx & 3;     // 16 cols each
    u16 ov[16];
    #pragma unroll
    for (int i=0;i<16;++i){
      float v;
      if (r < 128)       v = Al[r][q*16 + i];
      else if (r == 128) v = 1.f;
      else               v = 0.f;
      ov[i] = f2h(v);
    }
    u16* dst = &Ag[(size_t)r*Epad + e0 + q*16];
    uint4 o0, o1;
    o0.x=(u32)ov[0]|((u32)ov[1]<<16);  o0.y=(u32)ov[2]|((u32)ov[3]<<16);
    o0.z=(u32)ov[4]|((u32)ov[5]<<16);  o0.w=(u32)ov[6]|((u32)ov[7]<<16);
    o1.x=(u32)ov[8]|((u32)ov[9]<<16);  o1.y=(u32)ov[10]|((u32)ov[11]<<16);
    o1.z=(u32)ov[12]|((u32)ov[13]<<16); o1.w=(u32)ov[14]|((u32)ov[15]<<16);
    *(uint4*)dst = o0;
    *(uint4*)(dst+8) = o1;
  }
}

// ---------------------------------------------------------------------------
// Fused msg + segment_sum via MFMA, v6 (k-split): blockIdx.y owns output cols
// k in [y*16, y*16+16); runs ALL 33 c-chunks (full reduction) so each edge's
// msg slice is atomically added exactly ONCE (atomic traffic /4 vs c-split).
// 2-phase pipeline: stage next chunk (8 KB dbuf) + prefetch next A-scalars
// before computing current; one barrier per chunk.
__global__ __launch_bounds__(256,4) void k_msg_mfma(
    const int* __restrict__ ei, const float* __restrict__ h,
    const u16* __restrict__ Ag, const u16* __restrict__ Bg,
    float* __restrict__ agg, int E, int Epad)
{
  __shared__ __align__(16) u16 Blds[2][4096];   // 2 x 8 KB
  __shared__ int dstl[256];
  int t = threadIdx.x;
  int lane = t & 63;
  int wv = t >> 6;
  int e0 = blockIdx.x * 256;
  int y = blockIdx.y;                            // ct slice (output cols)

  {
    int e = e0 + t;
    dstl[t] = (e < E) ? ei[E + e] : -1;
  }

  // v-frags: direct gather from h + cvt to f16. Lane holds v[e][hb..hb+8),
  // e = wv*64 + rt*16 + (lane&15), hb = kh*32 + (lane>>4)*8.
  f16x8 vf[4][2];
  #pragma unroll
  for (int rt=0; rt<4; ++rt){
    int e = e0 + wv*64 + rt*16 + (lane&15);
    int src = (e < E) ? ei[e] : 0;
    const float* hp = &h[(size_t)src*64 + (lane>>4)*8];
    #pragma unroll
    for (int kh=0; kh<2; ++kh){
      float4 a = *(const float4*)&hp[kh*32];
      float4 b = *(const float4*)&hp[kh*32+4];
      f16x8 v;
      v[0]=(_Float16)a.x; v[1]=(_Float16)a.y; v[2]=(_Float16)a.z; v[3]=(_Float16)a.w;
      v[4]=(_Float16)b.x; v[5]=(_Float16)b.y; v[6]=(_Float16)b.z; v[7]=(_Float16)b.w;
      vf[rt][kh] = v;
    }
  }

  f32x4 acc[4];
  #pragma unroll
  for (int i=0;i<4;++i) acc[i] = (f32x4){0.f,0.f,0.f,0.f};

  const u16* Bbase = Bg + (size_t)y*NCH*4096;    // this y's contiguous region
  const u16* Arow  = Ag + e0 + wv*64 + (lane & 15);

  _Float16 arP[4][4], arN[4][4];
  // prologue: A-scalars for chunk 0, stage chunk 0 -> buf 0
  #pragma unroll
  for (int cl=0;cl<4;++cl)
    #pragma unroll
    for (int rt=0;rt<4;++rt)
      arP[cl][rt] = *(const _Float16*)&Arow[(size_t)cl*Epad + rt*16];
  {
    const char* g = (const char*)Bbase;
    #pragma unroll
    for (int r=0;r<2;++r)
      GLOAD_LDS16(g + r*4096 + wv*1024 + lane*16,
                  (char*)&Blds[0][0] + r*4096 + wv*1024);
  }
  __syncthreads();

  int cur = 0;
  for (int ch = 0; ch < NCH; ++ch){
    // issue next-chunk stage + next A-prefetch (overlaps current compute)
    if (ch + 1 < NCH){
      const char* g = (const char*)(Bbase + (size_t)(ch+1)*4096);
      #pragma unroll
      for (int r=0;r<2;++r)
        GLOAD_LDS16(g + r*4096 + wv*1024 + lane*16,
                    (char*)&Blds[cur^1][0] + r*4096 + wv*1024);
      const u16* Ac = Arow + (size_t)(ch+1)*CC*Epad;
      #pragma unroll
      for (int cl=0;cl<4;++cl)
        #pragma unroll
        for (int rt=0;rt<4;++rt)
          arN[cl][rt] = *(const _Float16*)&Ac[(size_t)cl*Epad + rt*16];
    }
    // compute current chunk from Blds[cur]
    const u16* Bb = &Blds[cur][0];
    #pragma unroll
    for (int cl=0; cl<CC; ++cl){
      f16x8 bf0 = *(const f16x8*)&Bb[(cl*2+0)*512 + lane*8];
      f16x8 bf1 = *(const f16x8*)&Bb[(cl*2+1)*512 + lane*8];
      #pragma unroll
      for (int rt=0; rt<4; ++rt){
        f16x8 g0 = vmul8(vf[rt][0], arP[cl][rt]);
        acc[rt] = __builtin_amdgcn_mfma_f32_16x16x32_f16(g0, bf0, acc[rt], 0,0,0);
      }
      #pragma unroll
      for (int rt=0; rt<4; ++rt){
        f16x8 g1 = vmul8(vf[rt][1], arP[cl][rt]);
        acc[rt] = __builtin_amdgcn_mfma_f32_16x16x32_f16(g1, bf1, acc[rt], 0,0,0);
      }
    }
    __syncthreads();          // waves done reading buf[cur]; next stage landed
    #pragma unroll
    for (int cl=0;cl<4;++cl)
      #pragma unroll
      for (int rt=0;rt<4;++rt)
        arP[cl][rt] = arN[cl][rt];
    cur ^= 1;
  }

  // epilogue: scatter-add (ONE atomic per edge-k). D layout: col=lane&15,
  // row=(lane>>4)*4+reg; k = y*16 + (lane&15).
  int kbase = y*16 + (lane & 15);
  #pragma unroll
  for (int rt=0; rt<4; ++rt){
    #pragma unroll
    for (int r=0; r<4; ++r){
      int el = wv*64 + rt*16 + (lane>>4)*4 + r;
      int dv = dstl[el];
      if (dv >= 0)
        unsafeAtomicAdd(&agg[(size_t)dv*64 + kbase], acc[rt][r]);
    }
  }
}

// ---------------------------------------------------------------------------
// combine: m = relu(agg + h@root + conv_b); GRU -> hnext; zeroes agg for the
// next iteration (each agg quad read+zeroed by exactly one thread).
__global__ __launch_bounds__(256) void k_combine(
    const float* __restrict__ hcur, float* __restrict__ agg,
    const float* __restrict__ root, const float* __restrict__ convb,
    const float* __restrict__ WihT, const float* __restrict__ WhhT,
    const float* __restrict__ bih, const float* __restrict__ bhh,
    float* __restrict__ hnext, int N)
{
  __shared__ float hsT[64][76];
  __shared__ float msT[64][76];
  __shared__ float ws[64][68];
  int t = threadIdx.x;
  int n0 = blockIdx.x * 64;

  for (int idx = t; idx < 4096; idx += 256){
    int ni = idx >> 6, k = idx & 63;
    int n = n0 + ni;
    hsT[k][ni] = (n < N) ? hcur[(size_t)n*64 + k] : 0.f;
  }
  for (int idx = t; idx < 4096; idx += 256)
    ws[idx >> 6][idx & 63] = root[idx];
  __syncthreads();

  int tq = t >> 4, tr = t & 15;
  int ni0 = tq*4, j0 = tr*4;

  {
    float acc[4][4];
    #pragma unroll
    for (int i=0;i<4;++i)
      #pragma unroll
      for (int j=0;j<4;++j) acc[i][j] = 0.f;
    for (int k = 0; k < 64; ++k){
      float4 a  = *(const float4*)&hsT[k][ni0];
      float4 wv = *(const float4*)&ws[k][j0];
      float av[4]={a.x,a.y,a.z,a.w}, bv[4]={wv.x,wv.y,wv.z,wv.w};
      #pragma unroll
      for (int i=0;i<4;++i)
        #pragma unroll
        for (int j=0;j<4;++j) acc[i][j] += av[i]*bv[j];
    }
    #pragma unroll
    for (int i=0;i<4;++i){
      int n = n0 + ni0 + i;
      float agv[4] = {0.f,0.f,0.f,0.f};
      if (n < N){
        float4 ag = *(const float4*)&agg[(size_t)n*64 + j0];
        agv[0]=ag.x; agv[1]=ag.y; agv[2]=ag.z; agv[3]=ag.w;
        *(float4*)&agg[(size_t)n*64 + j0] = make_float4(0.f,0.f,0.f,0.f);
      }
      #pragma unroll
      for (int j=0;j<4;++j)
        acc[i][j] = fmaxf(acc[i][j] + agv[j] + convb[j0+j], 0.f);
    }
    #pragma unroll
    for (int j=0;j<4;++j){
      float4 mv; mv.x=acc[0][j]; mv.y=acc[1][j]; mv.z=acc[2][j]; mv.w=acc[3][j];
      *(float4*)&msT[j0+j][ni0] = mv;
    }
  }

  float g[6][4][4];
  #pragma unroll
  for (int ct = 0; ct < 6; ++ct){
    __syncthreads();
    const float* WT = (ct < 3) ? WihT : WhhT;
    const float* bs = (ct < 3) ? bih  : bhh;
    int joff = (ct % 3) * 64;
    for (int idx = t; idx < 4096; idx += 256){
      int k = idx >> 6, j = idx & 63;
      ws[k][j] = WT[k*192 + joff + j];
    }
    __syncthreads();
    float acc[4][4];
    #pragma unroll
    for (int i=0;i<4;++i)
      #pragma unroll
      for (int j=0;j<4;++j) acc[i][j] = bs[joff + j0 + j];
    for (int k = 0; k < 64; ++k){
      float4 a  = (ct < 3) ? *(const float4*)&msT[k][ni0]
                           : *(const float4*)&hsT[k][ni0];
      float4 wv = *(const float4*)&ws[k][j0];
      float av[4]={a.x,a.y,a.z,a.w}, bv[4]={wv.x,wv.y,wv.z,wv.w};
      #pragma unroll
      for (int i=0;i<4;++i)
        #pragma unroll
        for (int j=0;j<4;++j) acc[i][j] += av[i]*bv[j];
    }
    #pragma unroll
    for (int i=0;i<4;++i)
      #pragma unroll
      for (int j=0;j<4;++j) g[ct][i][j] = acc[i][j];
  }

  #pragma unroll
  for (int i=0;i<4;++i){
    int n = n0 + ni0 + i;
    if (n < N){
      float hv[4];
      #pragma unroll
      for (int j=0;j<4;++j){
        float rr = sigm(g[0][i][j] + g[3][i][j]);
        float zz = sigm(g[1][i][j] + g[4][i][j]);
        float hold = hsT[j0+j][ni0+i];
        float nn = tanhx(g[2][i][j] + rr*g[5][i][j]);
        hv[j] = (1.f - zz)*nn + zz*hold;
      }
      float4 o; o.x=hv[0]; o.y=hv[1]; o.z=hv[2]; o.w=hv[3];
      *(float4*)&hnext[(size_t)n*64 + j0] = o;
    }
  }
}

// ---------------------------------------------------------------------------
__global__ __launch_bounds__(256) void k_final(
    const float* __restrict__ h, const int* __restrict__ x, const float* __restrict__ ext,
    const float* __restrict__ Wo1, const float* __restrict__ bo1,
    const float* __restrict__ Wo2, const float* __restrict__ bo2,
    const float* __restrict__ Wc1, const float* __restrict__ bc1,
    const float* __restrict__ Wc2, const float* __restrict__ bc2,
    float* __restrict__ fg_out, float* __restrict__ pred_out, int N)
{
  int lane = threadIdx.x & 63;
  int n = blockIdx.x*4 + (threadIdx.x >> 6);
  if (n >= N) return;
  float hv = h[(size_t)n*64 + lane];

  float acc = bo1[lane];
  for (int k = 0; k < 64; ++k) acc += __shfl(hv, k, 64) * Wo1[k*64 + lane];
  float t1 = fmaxf(acc, 0.f);
  float acc2 = bo2[lane];
  for (int k = 0; k < 64; ++k) acc2 += __shfl(t1, k, 64) * Wo2[k*64 + lane];
  float o = acc2;

  int idxn = x[n];
  float exv = 0.f;
  if (lane < NATOMS)          exv = (lane == idxn) ? 1.f : 0.f;
  else if (lane < NATOMS + 3) exv = ext[n*3 + (lane - NATOMS)];

  float ss = o*o + exv*exv;
  #pragma unroll
  for (int off = 32; off > 0; off >>= 1) ss += __shfl_xor(ss, off, 64);
  float rn = 1.f / fmaxf(sqrtf(ss), 1e-12f);
  float fg1 = o * rn, fg2 = exv * rn;

  fg_out[(size_t)n*91 + lane] = fg1;
  if (lane < 27) fg_out[(size_t)n*91 + 64 + lane] = fg2;

  float tq0 = bc1[lane], tq1 = bc1[64+lane], tq2 = bc1[128+lane], tq3 = bc1[192+lane];
  for (int f = 0; f < 64; ++f){
    float fv = __shfl(fg1, f, 64);
    const float* wp = &Wc1[(size_t)f*256 + lane];
    tq0 += fv*wp[0]; tq1 += fv*wp[64]; tq2 += fv*wp[128]; tq3 += fv*wp[192];
  }
  for (int f = 0; f < 27; ++f){
    float fv = __shfl(fg2, f, 64);
    const float* wp = &Wc1[(size_t)(64+f)*256 + lane];
    tq0 += fv*wp[0]; tq1 += fv*wp[64]; tq2 += fv*wp[128]; tq3 += fv*wp[192];
  }
  tq0 = fmaxf(tq0, 0.f); tq1 = fmaxf(tq1, 0.f);
  tq2 = fmaxf(tq2, 0.f); tq3 = fmaxf(tq3, 0.f);

  float pc[18];
  #pragma unroll
  for (int c = 0; c < 18; ++c){
    pc[c] = tq0*Wc2[lane*18 + c] + tq1*Wc2[(64+lane)*18 + c]
          + tq2*Wc2[(128+lane)*18 + c] + tq3*Wc2[(192+lane)*18 + c];
  }
  float wv = 0.f;
  #pragma unroll
  for (int c = 0; c < 18; ++c){
    float v = pc[c];
    #pragma unroll
    for (int off = 32; off > 0; off >>= 1) v += __shfl_xor(v, off, 64);
    if (lane == c) wv = v + bc2[c];
  }
  if (lane < 18) pred_out[(size_t)n*18 + lane] = wv;
}

// ---------------------------------------------------------------------------
extern "C" void kernel_launch(void* const* d_in, const int* in_sizes, int n_in,
                              void* d_out, int out_size, void* d_ws, size_t ws_size,
                              hipStream_t stream)
{
  const int*   x    = (const int*)d_in[0];
  const int*   ei   = (const int*)d_in[1];
  const float* ea   = (const float*)d_in[2];
  const float* ext  = (const float*)d_in[3];
  const float* embed= (const float*)d_in[4];
  const float* We1  = (const float*)d_in[5];
  const float* be1  = (const float*)d_in[6];
  const float* We2  = (const float*)d_in[7];
  const float* be2  = (const float*)d_in[8];
  const float* root = (const float*)d_in[9];
  const float* convb= (const float*)d_in[10];
  const float* Wih  = (const float*)d_in[11];
  const float* Whh  = (const float*)d_in[12];
  const float* bih  = (const float*)d_in[13];
  const float* bhh  = (const float*)d_in[14];
  const float* Wo1  = (const float*)d_in[15];
  const float* bo1  = (const float*)d_in[16];
  const float* Wo2  = (const float*)d_in[17];
  const float* bo2  = (const float*)d_in[18];
  const float* Wc1  = (const float*)d_in[19];
  const float* bc1  = (const float*)d_in[20];
  const float* Wc2  = (const float*)d_in[21];
  const float* bc2  = (const float*)d_in[22];
  int N = in_sizes[0];
  int E = in_sizes[1] / 2;
  float* out = (float*)d_out;
  float* fg_out = out;
  float* pred_out = out + (size_t)N*91;

  int nblk = (E + 255) / 256;
  int Epad = nblk * 256;

  char* w = (char*)d_ws;
  size_t remain = ws_size;
  auto alloc = [&](size_t bytes)->char*{
    size_t rb = (bytes + 255) & ~(size_t)255;
    if (rb > remain) return (char*)0;
    char* p = w; w += rb; remain -= rb; return p;
  };
  float* h_a  = (float*)alloc((size_t)N*64*4);
  float* h_b  = (float*)alloc((size_t)N*64*4);
  float* agg  = (float*)alloc((size_t)N*64*4);
  float* WihT = (float*)alloc(64*192*4);
  float* WhhT = (float*)alloc(64*192*4);
  u16*   Ag   = (u16*)alloc((size_t)CTOT*Epad*2);
  u16*   Bg   = (u16*)alloc((size_t)NCH*32768);
  if (!h_a || !h_b || !agg || !WihT || !WhhT || !Ag || !Bg) return;

  k_init_h<<<dim3((N*64 + 255)/256), dim3(256), 0, stream>>>(x, embed, ext, h_a, N);
  k_transpose_w<<<dim3(48), dim3(256), 0, stream>>>(Wih, Whh, WihT, WhhT);
  k_prep_B<<<dim3((NCH*32*64 + 255)/256), dim3(256), 0, stream>>>(We2, be2, Bg);
  k_edge_mlp<<<dim3(Epad/64), dim3(256), 0, stream>>>(ea, We1, be1, Ag, E, Epad);
  hipMemsetAsync(agg, 0, (size_t)N*64*4, stream);

  float* hc = h_a; float* hn = h_b;
  for (int it = 0; it < NITERS; ++it){
    k_msg_mfma<<<dim3(nblk, 4), dim3(256), 0, stream>>>(ei, hc, Ag, Bg, agg, E, Epad);
    k_combine<<<dim3((N + 63)/64), dim3(256), 0, stream>>>(
        hc, agg, root, convb, WihT, WhhT, bih, bhh, hn, N);
    float* tmp = hc; hc = hn; hn = tmp;
  }

  k_final<<<dim3((N + 3)/4), dim3(256), 0, stream>>>(
      hc, x, ext, Wo1, bo1, Wo2, bo2, Wc1, bc1, Wc2, bc2, fg_out, pred_out, N);
}